// Round 6
// baseline (266.257 us; speedup 1.0000x reference)
//
#include <hip/hip_runtime.h>
#include <math.h>

#define NPTS   12800
#define P_PIX  2560
#define NC     64          // compositing chunks (NPTS/NC = 200 pts/chunk)
#define CHUNK  200
#define RANK_CHUNK 800
#define RT     4           // rank keys per thread
#define MLP_PITCH 264      // ushorts per LDS row (256 + 8 pad)

typedef short short8 __attribute__((ext_vector_type(8)));
typedef float f32x4 __attribute__((ext_vector_type(4)));
typedef float f32x2 __attribute__((ext_vector_type(2)));

__device__ __forceinline__ unsigned short f2bf(float f) {
    unsigned int u = __float_as_uint(f);
    u += 0x7fffu + ((u >> 16) & 1u);   // RNE
    return (unsigned short)(u >> 16);
}

__device__ __forceinline__ float pack2h(float a, float b) {
    union { float f; _Float16 h[2]; } c;
    c.h[0] = (_Float16)a; c.h[1] = (_Float16)b;
    return c.f;
}
__device__ __forceinline__ float2 unpk2h(float w) {
    union { float f; _Float16 h[2]; } c; c.f = w;
    return make_float2((float)c.h[0], (float)c.h[1]);
}

// ---------------------------------------------------------------- per-point projection (+init)
__global__ __launch_bounds__(256) void prep_kernel(
    const float* __restrict__ xyz, const float* __restrict__ scales,
    const float* __restrict__ rots, const float* __restrict__ opacity,
    const float* __restrict__ viewmat, const float* __restrict__ intrins,
    unsigned long long* __restrict__ keys,
    float* __restrict__ pu, float* __restrict__ pv, float* __restrict__ prad,
    float* __restrict__ phA, float* __restrict__ phC, float* __restrict__ pnB,
    float* __restrict__ pop, int* __restrict__ rnk, float* __restrict__ out, int N) {
    int cam = blockIdx.y;
    int i = blockIdx.x * 256 + threadIdx.x;
    if (i >= N) return;
    int idx = cam * N + i;
    rnk[idx] = 0;
    if (idx == 0) out[0] = 0.0f;
    const float* vm = viewmat + cam * 16;
    const float* it = intrins + cam * 4;
    float fx = it[0], fy = it[1], cx = it[2], cy = it[3];
    float R00 = vm[0], R01 = vm[1], R02 = vm[2], t0 = vm[3];
    float R10 = vm[4], R11 = vm[5], R12 = vm[6], t1 = vm[7];
    float R20 = vm[8], R21 = vm[9], R22 = vm[10], t2 = vm[11];
    float X = xyz[i * 3], Y = xyz[i * 3 + 1], Z = xyz[i * 3 + 2];
    float x = R00 * X + R01 * Y + R02 * Z + t0;
    float y = R10 * X + R11 * Y + R12 * Z + t1;
    float z = R20 * X + R21 * Y + R22 * Z + t2;
    float zc = fmaxf(z, 0.001f);
    float iz = 1.0f / zc;
    float u = fx * x * iz + cx;
    float v = fy * y * iz + cy;
    float qw = rots[i * 4], qx = rots[i * 4 + 1], qy = rots[i * 4 + 2], qz = rots[i * 4 + 3];
    float qn = 1.0f / sqrtf(qw * qw + qx * qx + qy * qy + qz * qz);
    qw *= qn; qx *= qn; qy *= qn; qz *= qn;
    float s0 = expf(scales[i * 3]), s1 = expf(scales[i * 3 + 1]), s2 = expf(scales[i * 3 + 2]);
    float Rq[3][3] = {
        {1 - 2 * (qy * qy + qz * qz), 2 * (qx * qy - qw * qz), 2 * (qx * qz + qw * qy)},
        {2 * (qx * qy + qw * qz), 1 - 2 * (qx * qx + qz * qz), 2 * (qy * qz - qw * qx)},
        {2 * (qx * qz - qw * qy), 2 * (qy * qz + qw * qx), 1 - 2 * (qx * qx + qy * qy)}};
    float M[3][3];
    #pragma unroll
    for (int r = 0; r < 3; ++r) { M[r][0] = Rq[r][0] * s0; M[r][1] = Rq[r][1] * s1; M[r][2] = Rq[r][2] * s2; }
    float c3[3][3];
    #pragma unroll
    for (int a = 0; a < 3; ++a)
        #pragma unroll
        for (int b = 0; b < 3; ++b)
            c3[a][b] = M[a][0] * M[b][0] + M[a][1] * M[b][1] + M[a][2] * M[b][2];
    float Rw[3][3] = {{R00, R01, R02}, {R10, R11, R12}, {R20, R21, R22}};
    float Wt[3][3];
    #pragma unroll
    for (int a = 0; a < 3; ++a)
        #pragma unroll
        for (int b = 0; b < 3; ++b)
            Wt[a][b] = Rw[a][0] * c3[0][b] + Rw[a][1] * c3[1][b] + Rw[a][2] * c3[2][b];
    float cw[3][3];
    #pragma unroll
    for (int a = 0; a < 3; ++a)
        #pragma unroll
        for (int b = 0; b < 3; ++b)
            cw[a][b] = Wt[a][0] * Rw[b][0] + Wt[a][1] * Rw[b][1] + Wt[a][2] * Rw[b][2];
    float j00 = fx * iz, j02 = -fx * x * iz * iz;
    float j11 = fy * iz, j12 = -fy * y * iz * iz;
    float c00 = j00 * j00 * cw[0][0] + 2.0f * j00 * j02 * cw[0][2] + j02 * j02 * cw[2][2];
    float c01 = j00 * j11 * cw[0][1] + j00 * j12 * cw[0][2] + j02 * j11 * cw[2][1] + j02 * j12 * cw[2][2];
    float c11 = j11 * j11 * cw[1][1] + 2.0f * j11 * j12 * cw[1][2] + j12 * j12 * cw[2][2];
    float a = c00 + 0.3f, bq = c01, cc = c11 + 0.3f;
    float det = a * cc - bq * bq;
    float A = cc / det, Bc = -bq / det, Cc = a / det;
    float lmin = 0.5f * ((A + Cc) - sqrtf((A - Cc) * (A - Cc) + 4.0f * Bc * Bc));
    lmin = fmaxf(lmin, 1e-20f);
    float opv = (z > 0.2f) ? opacity[i] : 0.0f;
    float rad = -1.0f;
    if (opv > 0.0f) {
        float tcut = logf(opv) + 18.42f;  // ln(op * 1e8)
        if (tcut > 0.0f) rad = sqrtf(2.0f * tcut / lmin);
    }
    pu[idx] = u; pv[idx] = v; prad[idx] = rad;
    phA[idx] = -0.5f * A; phC[idx] = -0.5f * Cc; pnB[idx] = -Bc;
    pop[idx] = opv;
    unsigned int zb = __float_as_uint(z);
    zb = (zb & 0x80000000u) ? ~zb : (zb | 0x80000000u);
    keys[idx] = ((unsigned long long)zb << 32) | (unsigned int)i;
}

// ---------------------------------------------------------------- stable rank, RT keys/thread
__global__ __launch_bounds__(256) void rank_kernel(const unsigned long long* __restrict__ keys,
                                                   int* __restrict__ rnk, int N) {
    __shared__ unsigned long long sk[RANK_CHUNK];
    int cam = blockIdx.z;
    const unsigned long long* K = keys + (size_t)cam * N;
    int jbase = blockIdx.y * RANK_CHUNK;
    int jcnt = min(RANK_CHUNK, N - jbase);
    for (int t = threadIdx.x; t < jcnt; t += 256) sk[t] = K[jbase + t];
    __syncthreads();
    int i0 = blockIdx.x * (256 * RT) + threadIdx.x;
    unsigned long long ki[RT];
    int cnt[RT];
    #pragma unroll
    for (int t = 0; t < RT; ++t) {
        int i = i0 + t * 256;
        ki[t] = (i < N) ? K[i] : 0xFFFFFFFFFFFFFFFFull;
        cnt[t] = 0;
    }
    #pragma unroll 4
    for (int j = 0; j < jcnt; ++j) {
        unsigned long long kj = sk[j];
        #pragma unroll
        for (int t = 0; t < RT; ++t) cnt[t] += (kj < ki[t]) ? 1 : 0;
    }
    #pragma unroll
    for (int t = 0; t < RT; ++t) {
        int i = i0 + t * 256;
        if (i < N && cnt[t]) atomicAdd(rnk + (size_t)cam * N + i, cnt[t]);
    }
}

// ---------------------------------------------------------------- scatter into sorted packed records
// 16 floats (64 B): [u f32, v f32, (hA,hC) h2, (nB,op) h2, (f0,f1)..(f14,f15) h2 x8, (f16,0) h2, pad x3]
__global__ __launch_bounds__(256) void scatter_kernel(
    const int* __restrict__ rnk,
    const float* __restrict__ pu, const float* __restrict__ pv, const float* __restrict__ prad,
    const float* __restrict__ phA, const float* __restrict__ phC, const float* __restrict__ pnB,
    const float* __restrict__ pop,
    const float* __restrict__ feats, float* __restrict__ rec, float2* __restrict__ vr, int N) {
    int cam = blockIdx.y;
    int i = blockIdx.x * 256 + threadIdx.x;
    if (i >= N) return;
    int idx = cam * N + i;
    int r = rnk[idx];
    float* d = rec + ((size_t)cam * N + r) * 16;
    d[0] = pu[idx]; d[1] = pv[idx];
    d[2] = pack2h(phA[idx], phC[idx]);
    d[3] = pack2h(pnB[idx], pop[idx]);
    const float* f = feats + (size_t)i * 17;
    #pragma unroll
    for (int j = 0; j < 8; ++j) d[4 + j] = pack2h(f[2 * j], f[2 * j + 1]);
    d[12] = pack2h(f[16], 0.0f);
    d[13] = 0.0f; d[14] = 0.0f; d[15] = 0.0f;
    vr[(size_t)cam * N + r] = make_float2(pv[idx], prad[idx]);
}

// ---------------------------------------------------------------- build per-(cam,chunk,rowgroup4) pass lists
__global__ __launch_bounds__(256) void build_kernel(const float2* __restrict__ vr,
                                                    unsigned char* __restrict__ lists,
                                                    int* __restrict__ cnts, int N) {
    int gid = blockIdx.x * 4 + (threadIdx.x >> 6);   // list id 0..2*NC*10-1
    int lane = threadIdx.x & 63;
    int cam = gid / (NC * 10);
    int rem = gid - cam * (NC * 10);
    int ch = rem / 10, rg = rem - ch * 10;
    const float2* V = vr + (size_t)cam * N + ch * CHUNK;
    unsigned char* L = lists + (size_t)gid * CHUNK;
    float cy = (float)(rg * 4) + 1.5f;   // center of 4-row band
    int cnt = 0;
    for (int g = 0; g < CHUNK; g += 64) {
        int n = g + lane;
        bool pass = false;
        if (n < CHUNK) {
            float2 t = V[n];
            pass = fabsf(t.x - cy) <= t.y + 1.51f;
        }
        unsigned long long mask = __ballot(pass);
        int pre = __popcll(mask & ((1ull << lane) - 1ull));
        if (pass) L[cnt + pre] = (unsigned char)n;
        cnt += __popcll(mask);
    }
    if (lane == 0) cnts[gid] = cnt;
}

// ---------------------------------------------------------------- chunked alpha compositing
// 128-thread blocks, 2 waves, 4 rows per lane, packed 64 B records
__global__ __launch_bounds__(128) void splat_kernel(const float* __restrict__ rec,
                                                    const unsigned char* __restrict__ lists,
                                                    const int* __restrict__ cnts,
                                                    float* __restrict__ partT,
                                                    unsigned short* __restrict__ partS, int N) {
    __shared__ __align__(16) float4 sRec[CHUNK * 4];   // 12.8 KB
    __shared__ unsigned char sList[2 * CHUNK];
    __shared__ int sCnt[2];
    int cam = blockIdx.z, ch = blockIdx.y, pg = blockIdx.x;  // pg 0..4
    int tid = threadIdx.x, lane = tid & 63, wv = tid >> 6;   // wv 0..1
    const float4* src = (const float4*)(rec + ((size_t)cam * N + ch * CHUNK) * 16);
    for (int t = tid; t < CHUNK * 4; t += 128) sRec[t] = src[t];
    int lid0 = (cam * NC + ch) * 10 + pg * 2;
    const unsigned int* Lb = (const unsigned int*)(lists + (size_t)lid0 * CHUNK);
    unsigned int* sL = (unsigned int*)sList;
    for (int t = tid; t < 2 * CHUNK / 4; t += 128) sL[t] = Lb[t];
    if (tid < 2) sCnt[tid] = cnts[lid0 + tid];
    __syncthreads();
    int r0 = pg * 8 + wv * 4;                 // rows r0..r0+3
    int cnt = sCnt[wv];
    float px = (float)lane, py0 = (float)r0;
    float T0 = 1.0f, T1 = 1.0f, T2 = 1.0f, T3 = 1.0f;
    f32x2 accA[17], accB[17];                 // rows (0,1) and (2,3)
    #pragma unroll
    for (int c = 0; c < 17; ++c) { accA[c] = (f32x2){0.f, 0.f}; accB[c] = (f32x2){0.f, 0.f}; }
    const unsigned char* myL = sList + wv * CHUNK;
    const float* sRf = (const float*)sRec;
    for (int i = 0; i < cnt; ++i) {
        int n = myL[i];                        // wave-uniform -> LDS broadcast
        const float4* rp = sRec + n * 4;
        float4 q0 = rp[0];
        float2 g0 = unpk2h(q0.z);   // hA, hC
        float2 g1 = unpk2h(q0.w);   // nB, op
        float dx = q0.x - px;
        float dy0 = q0.y - py0, dy1 = dy0 - 1.0f, dy2 = dy0 - 2.0f, dy3 = dy0 - 3.0f;
        float hAdx = g0.x * dx;
        float p0 = fmaf(g0.y * dy0, dy0, dx * fmaf(g1.x, dy0, hAdx));
        float p1 = fmaf(g0.y * dy1, dy1, dx * fmaf(g1.x, dy1, hAdx));
        float p2 = fmaf(g0.y * dy2, dy2, dx * fmaf(g1.x, dy2, hAdx));
        float p3 = fmaf(g0.y * dy3, dy3, dx * fmaf(g1.x, dy3, hAdx));
        float a0 = fminf(0.99f, g1.y * __expf(fminf(p0, 0.0f)));
        float a1 = fminf(0.99f, g1.y * __expf(fminf(p1, 0.0f)));
        float a2 = fminf(0.99f, g1.y * __expf(fminf(p2, 0.0f)));
        float a3 = fminf(0.99f, g1.y * __expf(fminf(p3, 0.0f)));
        f32x2 wA = (f32x2){a0 * T0, a1 * T1};
        f32x2 wB = (f32x2){a2 * T2, a3 * T3};
        T0 = fmaf(-T0, a0, T0); T1 = fmaf(-T1, a1, T1);
        T2 = fmaf(-T2, a2, T2); T3 = fmaf(-T3, a3, T3);
        float4 q1 = rp[1], q2 = rp[2];
        float q3x = sRf[n * 16 + 12];
        float2 f01 = unpk2h(q1.x), f23 = unpk2h(q1.y), f45 = unpk2h(q1.z), f67 = unpk2h(q1.w);
        float2 f89 = unpk2h(q2.x), fab = unpk2h(q2.y), fcd = unpk2h(q2.z), fef = unpk2h(q2.w);
        float2 fg_ = unpk2h(q3x);
        accA[0]  += wA * f01.x;  accB[0]  += wB * f01.x;
        accA[1]  += wA * f01.y;  accB[1]  += wB * f01.y;
        accA[2]  += wA * f23.x;  accB[2]  += wB * f23.x;
        accA[3]  += wA * f23.y;  accB[3]  += wB * f23.y;
        accA[4]  += wA * f45.x;  accB[4]  += wB * f45.x;
        accA[5]  += wA * f45.y;  accB[5]  += wB * f45.y;
        accA[6]  += wA * f67.x;  accB[6]  += wB * f67.x;
        accA[7]  += wA * f67.y;  accB[7]  += wB * f67.y;
        accA[8]  += wA * f89.x;  accB[8]  += wB * f89.x;
        accA[9]  += wA * f89.y;  accB[9]  += wB * f89.y;
        accA[10] += wA * fab.x;  accB[10] += wB * fab.x;
        accA[11] += wA * fab.y;  accB[11] += wB * fab.y;
        accA[12] += wA * fcd.x;  accB[12] += wB * fcd.x;
        accA[13] += wA * fcd.y;  accB[13] += wB * fcd.y;
        accA[14] += wA * fef.x;  accB[14] += wB * fef.x;
        accA[15] += wA * fef.y;  accB[15] += wB * fef.y;
        accA[16] += wA * fg_.x;  accB[16] += wB * fg_.x;
    }
    size_t cbase = (size_t)(cam * NC + ch);
    size_t p0i = (size_t)r0 * 64 + lane;
    partT[cbase * P_PIX + p0i]       = T0;
    partT[cbase * P_PIX + p0i + 64]  = T1;
    partT[cbase * P_PIX + p0i + 128] = T2;
    partT[cbase * P_PIX + p0i + 192] = T3;
    _Float16* pS = (_Float16*)partS;
    #pragma unroll
    for (int c = 0; c < 17; ++c) {
        size_t b = (cbase * 17 + c) * P_PIX + p0i;
        pS[b]       = (_Float16)accA[c][0];
        pS[b + 64]  = (_Float16)accA[c][1];
        pS[b + 128] = (_Float16)accB[c][0];
        pS[b + 192] = (_Float16)accB[c][1];
    }
}

// ---------------------------------------------------------------- combine chunks -> fmap (T-prefix in-register)
__global__ __launch_bounds__(256) void combine_kernel(const float* __restrict__ partT,
                                                      const unsigned short* __restrict__ partS,
                                                      float* __restrict__ fmap) {
    int idx = blockIdx.x * 256 + threadIdx.x;
    if (idx >= 2 * 17 * P_PIX) return;
    int p = idx % P_PIX;
    int rem = idx / P_PIX;
    int c = rem % 17;
    int cam = rem / 17;
    const _Float16* pS = (const _Float16*)partS;
    float acc = 0.0f, Tp = 1.0f;
    #pragma unroll 8
    for (int k = 0; k < NC; ++k) {
        size_t cb = (size_t)(cam * NC + k);
        float Tk = partT[cb * P_PIX + p];
        float S = (float)pS[(cb * 17 + c) * P_PIX + p];
        acc = fmaf(Tp, S, acc);
        Tp *= Tk;
    }
    fmap[((size_t)cam * 17 + c) * P_PIX + p] = acc;
}

// ---------------------------------------------------------------- MLP: MFMA all 3 layers
__global__ __launch_bounds__(256, 2) void mlp_kernel(
    const float* __restrict__ embd, const float* __restrict__ sfeat,
    const float* __restrict__ W1, const float* __restrict__ b1,
    const float* __restrict__ g1, const float* __restrict__ be1,
    const float* __restrict__ W2, const float* __restrict__ b2,
    const float* __restrict__ g2, const float* __restrict__ be2,
    const float* __restrict__ W3, const float* __restrict__ b3,
    float* __restrict__ sed, float* __restrict__ ldf) {
    __shared__ __align__(16) unsigned short smem[2 * 64 * MLP_PITCH];
    unsigned short* sX = smem;
    unsigned short* sW = smem + 64 * MLP_PITCH;
    int tid = threadIdx.x, lane = tid & 63, wv = tid >> 6;
    int m = lane & 15, kq = lane >> 4, q4 = kq * 4;
    int tile = blockIdx.x;
    const float* xbase;
    if (tile < 80) {
        int cam = tile / 40; int r = tile - cam * 40;
        int ri = (r * 8) / 5;  // floor(r*64/40)
        xbase = embd + (size_t)cam * 256 * 4096 + ri * 64;
    } else {
        int tt = tile - 80; int cam = tt >> 6;
        xbase = sfeat + (size_t)cam * 256 * 4096 + (tt & 63) * 64;
    }
    const float4* xf4 = (const float4*)xbase;
    for (int idx = tid; idx < 4096; idx += 256) {
        int k = idx >> 4, q = idx & 15;
        float4 xv = xf4[(size_t)k * 1024 + q];
        int r = q * 4;
        sX[(r + 0) * MLP_PITCH + k] = f2bf(xv.x);
        sX[(r + 1) * MLP_PITCH + k] = f2bf(xv.y);
        sX[(r + 2) * MLP_PITCH + k] = f2bf(xv.z);
        sX[(r + 3) * MLP_PITCH + k] = f2bf(xv.w);
    }
    const float4* wf4 = (const float4*)W1;
    for (int idx = tid; idx < 4096; idx += 256) {
        float4 wvv = wf4[idx];
        int n = idx >> 6, kk = (idx & 63) * 4;
        uint2 pk;
        pk.x = (unsigned int)f2bf(wvv.x) | ((unsigned int)f2bf(wvv.y) << 16);
        pk.y = (unsigned int)f2bf(wvv.z) | ((unsigned int)f2bf(wvv.w) << 16);
        *(uint2*)&sW[n * MLP_PITCH + kk] = pk;
    }
    float b1v[4], g1v[4], be1v[4], b2v[4], g2v[4], be2v[4];
    #pragma unroll
    for (int nt = 0; nt < 4; ++nt) {
        int c = nt * 16 + m;
        b1v[nt] = b1[c]; g1v[nt] = g1[c]; be1v[nt] = be1[c];
        b2v[nt] = b2[c]; g2v[nt] = g2[c]; be2v[nt] = be2[c];
    }
    __syncthreads();
    f32x4 acc[4];
    #pragma unroll
    for (int nt = 0; nt < 4; ++nt) acc[nt] = (f32x4){0.f, 0.f, 0.f, 0.f};
    const unsigned short* aptr = sX + (wv * 16 + m) * MLP_PITCH + kq * 8;
    const unsigned short* bptr = sW + m * MLP_PITCH + kq * 8;
    #pragma unroll
    for (int ks = 0; ks < 8; ++ks) {
        short8 af = *(const short8*)(aptr + ks * 32);
        #pragma unroll
        for (int nt = 0; nt < 4; ++nt) {
            short8 bf = *(const short8*)(bptr + nt * 16 * MLP_PITCH + ks * 32);
            acc[nt] = __builtin_amdgcn_mfma_f32_16x16x32_bf16(af, bf, acc[nt], 0, 0, 0);
        }
    }
    __syncthreads();   // done reading sX/sW -> safe to alias
    unsigned short* hbuf  = smem + wv * 16 * 72;
    unsigned short* hbuf2 = smem + (4 + wv) * 16 * 72;
    unsigned short* W2b = sW;
    unsigned short* W3b = sW + 64 * 72;
    for (int i = tid; i < 4096; i += 256)
        W2b[(i >> 6) * 72 + (i & 63)] = f2bf(W2[i]);
    for (int i = tid; i < 2048; i += 256) {
        int n = i >> 6, k = i & 63;
        W3b[n * 72 + k] = (n < 17) ? f2bf(W3[n * 64 + k]) : 0;
    }
    #pragma unroll
    for (int rg = 0; rg < 4; ++rg) {
        float h0 = acc[0][rg] + b1v[0], h1 = acc[1][rg] + b1v[1];
        float h2 = acc[2][rg] + b1v[2], h3 = acc[3][rg] + b1v[3];
        float s = (h0 + h1) + (h2 + h3);
        s += __shfl_xor(s, 1); s += __shfl_xor(s, 2);
        s += __shfl_xor(s, 4); s += __shfl_xor(s, 8);
        float mu = s * (1.0f / 64.0f);
        float d0 = h0 - mu, d1 = h1 - mu, d2 = h2 - mu, d3 = h3 - mu;
        float vs = (d0 * d0 + d1 * d1) + (d2 * d2 + d3 * d3);
        vs += __shfl_xor(vs, 1); vs += __shfl_xor(vs, 2);
        vs += __shfl_xor(vs, 4); vs += __shfl_xor(vs, 8);
        float rstd = 1.0f / sqrtf(vs * (1.0f / 64.0f) + 1e-5f);
        float hn0 = d0 * rstd * g1v[0] + be1v[0]; hn0 = fmaxf(hn0, 0.01f * hn0);
        float hn1 = d1 * rstd * g1v[1] + be1v[1]; hn1 = fmaxf(hn1, 0.01f * hn1);
        float hn2 = d2 * rstd * g1v[2] + be1v[2]; hn2 = fmaxf(hn2, 0.01f * hn2);
        float hn3 = d3 * rstd * g1v[3] + be1v[3]; hn3 = fmaxf(hn3, 0.01f * hn3);
        int rr = (q4 + rg) * 72 + m;
        hbuf[rr] = f2bf(hn0); hbuf[rr + 16] = f2bf(hn1);
        hbuf[rr + 32] = f2bf(hn2); hbuf[rr + 48] = f2bf(hn3);
    }
    __syncthreads();
    f32x4 acc2[4];
    #pragma unroll
    for (int nt = 0; nt < 4; ++nt) acc2[nt] = (f32x4){0.f, 0.f, 0.f, 0.f};
    const unsigned short* a2p = hbuf + m * 72 + kq * 8;
    #pragma unroll
    for (int ks = 0; ks < 2; ++ks) {
        short8 af = *(const short8*)(a2p + ks * 32);
        #pragma unroll
        for (int nt = 0; nt < 4; ++nt) {
            short8 bf = *(const short8*)(W2b + (nt * 16 + m) * 72 + kq * 8 + ks * 32);
            acc2[nt] = __builtin_amdgcn_mfma_f32_16x16x32_bf16(af, bf, acc2[nt], 0, 0, 0);
        }
    }
    #pragma unroll
    for (int rg = 0; rg < 4; ++rg) {
        float h0 = acc2[0][rg] + b2v[0], h1 = acc2[1][rg] + b2v[1];
        float h2 = acc2[2][rg] + b2v[2], h3 = acc2[3][rg] + b2v[3];
        float s = (h0 + h1) + (h2 + h3);
        s += __shfl_xor(s, 1); s += __shfl_xor(s, 2);
        s += __shfl_xor(s, 4); s += __shfl_xor(s, 8);
        float mu = s * (1.0f / 64.0f);
        float d0 = h0 - mu, d1 = h1 - mu, d2 = h2 - mu, d3 = h3 - mu;
        float vs = (d0 * d0 + d1 * d1) + (d2 * d2 + d3 * d3);
        vs += __shfl_xor(vs, 1); vs += __shfl_xor(vs, 2);
        vs += __shfl_xor(vs, 4); vs += __shfl_xor(vs, 8);
        float rstd = 1.0f / sqrtf(vs * (1.0f / 64.0f) + 1e-5f);
        float hn0 = d0 * rstd * g2v[0] + be2v[0]; hn0 = fmaxf(hn0, 0.01f * hn0);
        float hn1 = d1 * rstd * g2v[1] + be2v[1]; hn1 = fmaxf(hn1, 0.01f * hn1);
        float hn2 = d2 * rstd * g2v[2] + be2v[2]; hn2 = fmaxf(hn2, 0.01f * hn2);
        float hn3 = d3 * rstd * g2v[3] + be2v[3]; hn3 = fmaxf(hn3, 0.01f * hn3);
        int rr = (q4 + rg) * 72 + m;
        hbuf2[rr] = f2bf(hn0); hbuf2[rr + 16] = f2bf(hn1);
        hbuf2[rr + 32] = f2bf(hn2); hbuf2[rr + 48] = f2bf(hn3);
    }
    f32x4 acc3[2];
    acc3[0] = (f32x4){0.f, 0.f, 0.f, 0.f};
    acc3[1] = (f32x4){0.f, 0.f, 0.f, 0.f};
    const unsigned short* a3p = hbuf2 + m * 72 + kq * 8;
    #pragma unroll
    for (int ks = 0; ks < 2; ++ks) {
        short8 af = *(const short8*)(a3p + ks * 32);
        #pragma unroll
        for (int nt = 0; nt < 2; ++nt) {
            short8 bf = *(const short8*)(W3b + (nt * 16 + m) * 72 + kq * 8 + ks * 32);
            acc3[nt] = __builtin_amdgcn_mfma_f32_16x16x32_bf16(af, bf, acc3[nt], 0, 0, 0);
        }
    }
    #pragma unroll
    for (int nt = 0; nt < 2; ++nt) {
        int c = nt * 16 + m;
        if (c < 17) {
            float b3v = b3[c];
            #pragma unroll
            for (int rg = 0; rg < 4; ++rg) {
                int row = tile * 64 + wv * 16 + q4 + rg;
                float val = acc3[nt][rg] + b3v;
                if (row < 5120) {
                    int cam = row / 2560; int p = row - cam * 2560;
                    sed[((size_t)cam * 2560 + p) * 17 + c] = val;
                } else {
                    int rr = row - 5120; int cam = rr >> 12; int t = rr & 4095;
                    ldf[((size_t)cam * 17 + c) * 4096 + t] = val;
                }
            }
        }
    }
}

// ---------------------------------------------------------------- mask prototypes
__global__ __launch_bounds__(256) void proto_kernel(const float* __restrict__ masks,
                                                    const float* __restrict__ ldf,
                                                    float* __restrict__ proto) {
    int cam = blockIdx.y, m = blockIdx.x;
    const float* M = masks + ((size_t)cam * 16 + m) * 40000;
    float acc[18];
    #pragma unroll
    for (int j = 0; j < 18; ++j) acc[j] = 0.0f;
    for (int t = threadIdx.x; t < 4096; t += 256) {
        int h = t >> 6, w = t & 63;
        int rh = (h * 25) >> 3, rw = (w * 25) >> 3;
        float lv = M[rh * 200 + rw];
        if (lv != 0.0f) {
            acc[17] += lv;
            const float* L = ldf + (size_t)cam * 17 * 4096 + t;
            #pragma unroll
            for (int c = 0; c < 17; ++c) acc[c] = fmaf(lv, L[(size_t)c * 4096], acc[c]);
        }
    }
    __shared__ float red[4][18];
    int lane = threadIdx.x & 63, wv = threadIdx.x >> 6;
    #pragma unroll
    for (int j = 0; j < 18; ++j) {
        float v = acc[j];
        #pragma unroll
        for (int o = 32; o; o >>= 1) v += __shfl_xor(v, o);
        if (lane == 0) red[wv][j] = v;
    }
    __syncthreads();
    if (threadIdx.x < 17) {
        float sacc = red[0][threadIdx.x] + red[1][threadIdx.x] + red[2][threadIdx.x] + red[3][threadIdx.x];
        float ms = red[0][17] + red[1][17] + red[2][17] + red[3][17];
        proto[((size_t)cam * 16 + m) * 17 + threadIdx.x] = sacc / fmaxf(ms, 1e-6f);
    }
}

__device__ __forceinline__ void block_atomic_add(float v, float* target) {
    #pragma unroll
    for (int o = 32; o; o >>= 1) v += __shfl_xor(v, o);
    __shared__ float sred[4];
    int lane = threadIdx.x & 63, wv = threadIdx.x >> 6;
    if (lane == 0) sred[wv] = v;
    __syncthreads();
    if (threadIdx.x == 0) atomicAdd(target, sred[0] + sred[1] + sred[2] + sred[3]);
}

// ---------------------------------------------------------------- BCE + L1 loss (fused)
__global__ __launch_bounds__(256) void bce_kernel(const float* __restrict__ masks,
                                                  const float* __restrict__ proto,
                                                  const float* __restrict__ fmap,
                                                  const float* __restrict__ sed,
                                                  float* __restrict__ out) {
    int idx = blockIdx.x * 256 + threadIdx.x;
    int p = idx % P_PIX;
    int rem = idx / P_PIX;
    int m = rem & 15, cam = rem >> 4;
    const float* pr = proto + ((size_t)cam * 16 + m) * 17;
    float f[17];
    #pragma unroll
    for (int c = 0; c < 17; ++c) f[c] = fmap[((size_t)cam * 17 + c) * P_PIX + p];
    float sdot = 0;
    #pragma unroll
    for (int c = 0; c < 17; ++c) sdot = fmaf(pr[c], f[c], sdot);
    float prob = 1.0f / (1.0f + __expf(-sdot));
    int px = p & 63, py = p >> 6;
    float src_r = (py + 0.5f) * 5.0f - 0.5f;
    float src_c = (px + 0.5f) * 3.125f - 0.5f;
    int r0 = (int)fminf(fmaxf(floorf(src_r), 0.0f), 199.0f);
    int r1 = min(r0 + 1, 199);
    float wr = fminf(fmaxf(src_r - (float)r0, 0.0f), 1.0f);
    int c0 = (int)fminf(fmaxf(floorf(src_c), 0.0f), 199.0f);
    int c1 = min(c0 + 1, 199);
    float wc = fminf(fmaxf(src_c - (float)c0, 0.0f), 1.0f);
    const float* M = masks + ((size_t)cam * 16 + m) * 40000;
    float v00 = M[r0 * 200 + c0], v01 = M[r0 * 200 + c1];
    float v10 = M[r1 * 200 + c0], v11 = M[r1 * 200 + c1];
    float xr0 = v00 * (1.0f - wr) + v10 * wr;
    float xr1 = v01 * (1.0f - wr) + v11 * wr;
    float frm = xr0 * (1.0f - wc) + xr1 * wc;
    frm = (frm <= 0.5f) ? 0.0f : frm;
    float bce = frm * __logf(prob + 1e-8f) + (1.0f - frm) * __logf(1.0f - prob + 1e-8f);
    float val = bce * (-1.0f / (16.0f * 2560.0f * 2.0f));
    if (m == 0) {   // L1 term, once per (cam, p)
        float ssum = 0.0f;
        const float* sp = sed + ((size_t)cam * P_PIX + p) * 17;
        #pragma unroll
        for (int c = 0; c < 17; ++c) ssum += fabsf(f[c] - sp[c]);
        val += ssum * (1.0f / (43520.0f * 2.0f));
    }
    block_atomic_add(val, out);
}

// ================================================================ launch
extern "C" void kernel_launch(void* const* d_in, const int* in_sizes, int n_in,
                              void* d_out, int out_size, void* d_ws, size_t ws_size,
                              hipStream_t stream) {
    const float* voxel_feats = (const float*)d_in[0];
    const float* opacity     = (const float*)d_in[1];
    const float* sam_embd    = (const float*)d_in[2];
    const float* sam_features= (const float*)d_in[3];
    const float* sam_masks   = (const float*)d_in[4];
    const float* viewmat     = (const float*)d_in[5];
    const float* intrins     = (const float*)d_in[6];
    const float* pc_xyz      = (const float*)d_in[7];
    const float* scales      = (const float*)d_in[8];
    const float* rots        = (const float*)d_in[9];
    const float* W1 = (const float*)d_in[10], *b1 = (const float*)d_in[11];
    const float* g1 = (const float*)d_in[12], *be1 = (const float*)d_in[13];
    const float* W2 = (const float*)d_in[14], *b2 = (const float*)d_in[15];
    const float* g2 = (const float*)d_in[16], *be2 = (const float*)d_in[17];
    const float* W3 = (const float*)d_in[18], *b3 = (const float*)d_in[19];
    float* out = (float*)d_out;
    const int N = in_sizes[7] / 3;  // 12800

    char* w = (char*)d_ws;
    size_t off = 0;
    auto alloc = [&](size_t bytes) -> void* {
        off = (off + 255) & ~(size_t)255;
        void* p = w + off; off += bytes; return p;
    };
    int* rnk  = (int*)alloc((size_t)2 * N * sizeof(int));
    unsigned long long* keys = (unsigned long long*)alloc((size_t)2 * N * 8);
    float* params = (float*)alloc((size_t)7 * 2 * N * 4);
    float* pu  = params,           *pv  = params + 2 * N,  *prad = params + 4 * N;
    float* phA = params + 6 * N,   *phC = params + 8 * N,  *pnB  = params + 10 * N;
    float* pop = params + 12 * N;
    float* rec   = (float*)alloc((size_t)2 * N * 16 * 4);
    float2* vr   = (float2*)alloc((size_t)2 * N * 8);
    float* partT = (float*)alloc((size_t)2 * NC * P_PIX * 4);
    unsigned short* partS = (unsigned short*)alloc((size_t)2 * NC * 17 * P_PIX * 2);
    float* fmap  = (float*)alloc((size_t)2 * 17 * P_PIX * 4);
    float* sed   = (float*)alloc((size_t)2 * P_PIX * 17 * 4);
    float* ldf   = (float*)alloc((size_t)2 * 17 * 4096 * 4);
    float* proto = (float*)alloc((size_t)2 * 16 * 17 * 4);
    unsigned char* lists = (unsigned char*)alloc((size_t)2 * NC * 10 * CHUNK);
    int* cnts = (int*)alloc((size_t)2 * NC * 10 * sizeof(int));

    dim3 gprep((N + 255) / 256, 2);
    prep_kernel<<<gprep, 256, 0, stream>>>(pc_xyz, scales, rots, opacity, viewmat, intrins,
                                           keys, pu, pv, prad, phA, phC, pnB, pop, rnk, out, N);
    dim3 grank((N + 256 * RT - 1) / (256 * RT), (N + RANK_CHUNK - 1) / RANK_CHUNK, 2);
    rank_kernel<<<grank, 256, 0, stream>>>(keys, rnk, N);
    scatter_kernel<<<gprep, 256, 0, stream>>>(rnk, pu, pv, prad, phA, phC, pnB, pop,
                                              voxel_feats, rec, vr, N);
    build_kernel<<<2 * NC * 10 / 4, 256, 0, stream>>>(vr, lists, cnts, N);
    dim3 gsplat(5, NC, 2);
    splat_kernel<<<gsplat, 128, 0, stream>>>(rec, lists, cnts, partT, partS, N);
    mlp_kernel<<<208, 256, 0, stream>>>(sam_embd, sam_features, W1, b1, g1, be1,
                                        W2, b2, g2, be2, W3, b3, sed, ldf);
    combine_kernel<<<(2 * 17 * P_PIX + 255) / 256, 256, 0, stream>>>(partT, partS, fmap);
    dim3 gproto(16, 2);
    proto_kernel<<<gproto, 256, 0, stream>>>(sam_masks, ldf, proto);
    bce_kernel<<<(2 * 16 * P_PIX) / 256, 256, 0, stream>>>(sam_masks, proto, fmap, sed, out);
}

// Round 7
// 248.481 us; speedup vs baseline: 1.0715x; 1.0715x over previous
//
#include <hip/hip_runtime.h>
#include <math.h>

#define NPTS   12800
#define P_PIX  2560
#define NC     128         // compositing chunks (NPTS/NC = 100 pts/chunk)
#define CHUNK  100
#define NRG    10          // 4-row groups (40 rows)
#define RANK_CHUNK 800
#define RT     4           // rank keys per thread
#define MLP_PITCH 264      // ushorts per LDS row (256 + 8 pad)

typedef short short8 __attribute__((ext_vector_type(8)));
typedef float f32x4 __attribute__((ext_vector_type(4)));
typedef float f32x2 __attribute__((ext_vector_type(2)));

__device__ __forceinline__ unsigned short f2bf(float f) {
    unsigned int u = __float_as_uint(f);
    u += 0x7fffu + ((u >> 16) & 1u);   // RNE
    return (unsigned short)(u >> 16);
}

__device__ __forceinline__ float pack2h(float a, float b) {
    union { float f; _Float16 h[2]; } c;
    c.h[0] = (_Float16)a; c.h[1] = (_Float16)b;
    return c.f;
}
__device__ __forceinline__ float2 unpk2h(float w) {
    union { float f; _Float16 h[2]; } c; c.f = w;
    return make_float2((float)c.h[0], (float)c.h[1]);
}

// ---------------------------------------------------------------- per-point projection (+init)
__global__ __launch_bounds__(256) void prep_kernel(
    const float* __restrict__ xyz, const float* __restrict__ scales,
    const float* __restrict__ rots, const float* __restrict__ opacity,
    const float* __restrict__ viewmat, const float* __restrict__ intrins,
    unsigned long long* __restrict__ keys,
    float* __restrict__ pu, float* __restrict__ pv, float* __restrict__ prad,
    float* __restrict__ phA, float* __restrict__ phC, float* __restrict__ pnB,
    float* __restrict__ pop, int* __restrict__ rnk, float* __restrict__ out, int N) {
    int cam = blockIdx.y;
    int i = blockIdx.x * 256 + threadIdx.x;
    if (i >= N) return;
    int idx = cam * N + i;
    rnk[idx] = 0;
    if (idx == 0) out[0] = 0.0f;
    const float* vm = viewmat + cam * 16;
    const float* it = intrins + cam * 4;
    float fx = it[0], fy = it[1], cx = it[2], cy = it[3];
    float R00 = vm[0], R01 = vm[1], R02 = vm[2], t0 = vm[3];
    float R10 = vm[4], R11 = vm[5], R12 = vm[6], t1 = vm[7];
    float R20 = vm[8], R21 = vm[9], R22 = vm[10], t2 = vm[11];
    float X = xyz[i * 3], Y = xyz[i * 3 + 1], Z = xyz[i * 3 + 2];
    float x = R00 * X + R01 * Y + R02 * Z + t0;
    float y = R10 * X + R11 * Y + R12 * Z + t1;
    float z = R20 * X + R21 * Y + R22 * Z + t2;
    float zc = fmaxf(z, 0.001f);
    float iz = 1.0f / zc;
    float u = fx * x * iz + cx;
    float v = fy * y * iz + cy;
    float qw = rots[i * 4], qx = rots[i * 4 + 1], qy = rots[i * 4 + 2], qz = rots[i * 4 + 3];
    float qn = 1.0f / sqrtf(qw * qw + qx * qx + qy * qy + qz * qz);
    qw *= qn; qx *= qn; qy *= qn; qz *= qn;
    float s0 = expf(scales[i * 3]), s1 = expf(scales[i * 3 + 1]), s2 = expf(scales[i * 3 + 2]);
    float Rq[3][3] = {
        {1 - 2 * (qy * qy + qz * qz), 2 * (qx * qy - qw * qz), 2 * (qx * qz + qw * qy)},
        {2 * (qx * qy + qw * qz), 1 - 2 * (qx * qx + qz * qz), 2 * (qy * qz - qw * qx)},
        {2 * (qx * qz - qw * qy), 2 * (qy * qz + qw * qx), 1 - 2 * (qx * qx + qy * qy)}};
    float M[3][3];
    #pragma unroll
    for (int r = 0; r < 3; ++r) { M[r][0] = Rq[r][0] * s0; M[r][1] = Rq[r][1] * s1; M[r][2] = Rq[r][2] * s2; }
    float c3[3][3];
    #pragma unroll
    for (int a = 0; a < 3; ++a)
        #pragma unroll
        for (int b = 0; b < 3; ++b)
            c3[a][b] = M[a][0] * M[b][0] + M[a][1] * M[b][1] + M[a][2] * M[b][2];
    float Rw[3][3] = {{R00, R01, R02}, {R10, R11, R12}, {R20, R21, R22}};
    float Wt[3][3];
    #pragma unroll
    for (int a = 0; a < 3; ++a)
        #pragma unroll
        for (int b = 0; b < 3; ++b)
            Wt[a][b] = Rw[a][0] * c3[0][b] + Rw[a][1] * c3[1][b] + Rw[a][2] * c3[2][b];
    float cw[3][3];
    #pragma unroll
    for (int a = 0; a < 3; ++a)
        #pragma unroll
        for (int b = 0; b < 3; ++b)
            cw[a][b] = Wt[a][0] * Rw[b][0] + Wt[a][1] * Rw[b][1] + Wt[a][2] * Rw[b][2];
    float j00 = fx * iz, j02 = -fx * x * iz * iz;
    float j11 = fy * iz, j12 = -fy * y * iz * iz;
    float c00 = j00 * j00 * cw[0][0] + 2.0f * j00 * j02 * cw[0][2] + j02 * j02 * cw[2][2];
    float c01 = j00 * j11 * cw[0][1] + j00 * j12 * cw[0][2] + j02 * j11 * cw[2][1] + j02 * j12 * cw[2][2];
    float c11 = j11 * j11 * cw[1][1] + 2.0f * j11 * j12 * cw[1][2] + j12 * j12 * cw[2][2];
    float a = c00 + 0.3f, bq = c01, cc = c11 + 0.3f;
    float det = a * cc - bq * bq;
    float A = cc / det, Bc = -bq / det, Cc = a / det;
    float lmin = 0.5f * ((A + Cc) - sqrtf((A - Cc) * (A - Cc) + 4.0f * Bc * Bc));
    lmin = fmaxf(lmin, 1e-20f);
    float opv = (z > 0.2f) ? opacity[i] : 0.0f;
    float rad = -1.0f;
    if (opv > 0.0f) {
        float tcut = logf(opv) + 18.42f;  // ln(op * 1e8)
        if (tcut > 0.0f) rad = sqrtf(2.0f * tcut / lmin);
    }
    pu[idx] = u; pv[idx] = v; prad[idx] = rad;
    phA[idx] = -0.5f * A; phC[idx] = -0.5f * Cc; pnB[idx] = -Bc;
    pop[idx] = opv;
    unsigned int zb = __float_as_uint(z);
    zb = (zb & 0x80000000u) ? ~zb : (zb | 0x80000000u);
    keys[idx] = ((unsigned long long)zb << 32) | (unsigned int)i;
}

// ---------------------------------------------------------------- stable rank, RT keys/thread
__global__ __launch_bounds__(256) void rank_kernel(const unsigned long long* __restrict__ keys,
                                                   int* __restrict__ rnk, int N) {
    __shared__ unsigned long long sk[RANK_CHUNK];
    int cam = blockIdx.z;
    const unsigned long long* K = keys + (size_t)cam * N;
    int jbase = blockIdx.y * RANK_CHUNK;
    int jcnt = min(RANK_CHUNK, N - jbase);
    for (int t = threadIdx.x; t < jcnt; t += 256) sk[t] = K[jbase + t];
    __syncthreads();
    int i0 = blockIdx.x * (256 * RT) + threadIdx.x;
    unsigned long long ki[RT];
    int cnt[RT];
    #pragma unroll
    for (int t = 0; t < RT; ++t) {
        int i = i0 + t * 256;
        ki[t] = (i < N) ? K[i] : 0xFFFFFFFFFFFFFFFFull;
        cnt[t] = 0;
    }
    #pragma unroll 4
    for (int j = 0; j < jcnt; ++j) {
        unsigned long long kj = sk[j];
        #pragma unroll
        for (int t = 0; t < RT; ++t) cnt[t] += (kj < ki[t]) ? 1 : 0;
    }
    #pragma unroll
    for (int t = 0; t < RT; ++t) {
        int i = i0 + t * 256;
        if (i < N && cnt[t]) atomicAdd(rnk + (size_t)cam * N + i, cnt[t]);
    }
}

// ---------------------------------------------------------------- scatter into sorted packed records
// 16 floats (64 B): [u f32, v f32, (hA,hC) h2, (nB,op) h2, (f0,f1)..(f14,f15) h2 x8, (f16,0) h2, pad x3]
__global__ __launch_bounds__(256) void scatter_kernel(
    const int* __restrict__ rnk,
    const float* __restrict__ pu, const float* __restrict__ pv, const float* __restrict__ prad,
    const float* __restrict__ phA, const float* __restrict__ phC, const float* __restrict__ pnB,
    const float* __restrict__ pop,
    const float* __restrict__ feats, float* __restrict__ rec, float2* __restrict__ vr, int N) {
    int cam = blockIdx.y;
    int i = blockIdx.x * 256 + threadIdx.x;
    if (i >= N) return;
    int idx = cam * N + i;
    int r = rnk[idx];
    float* d = rec + ((size_t)cam * N + r) * 16;
    d[0] = pu[idx]; d[1] = pv[idx];
    d[2] = pack2h(phA[idx], phC[idx]);
    d[3] = pack2h(pnB[idx], pop[idx]);
    const float* f = feats + (size_t)i * 17;
    #pragma unroll
    for (int j = 0; j < 8; ++j) d[4 + j] = pack2h(f[2 * j], f[2 * j + 1]);
    d[12] = pack2h(f[16], 0.0f);
    d[13] = 0.0f; d[14] = 0.0f; d[15] = 0.0f;
    vr[(size_t)cam * N + r] = make_float2(pv[idx], prad[idx]);
}

// ---------------------------------------------------------------- expand: compact passing records
// per-(cam, chunk, 4-row group) contiguous streams; ballot compaction preserves depth order
__global__ __launch_bounds__(256) void expand_kernel(const float2* __restrict__ vr,
                                                     const float* __restrict__ rec,
                                                     float* __restrict__ cstream,
                                                     int* __restrict__ cnts, int N) {
    int gid = blockIdx.x * 4 + (threadIdx.x >> 6);   // list id 0..2*NC*NRG-1
    int lane = threadIdx.x & 63;
    int cam = gid / (NC * NRG);
    int rem = gid - cam * (NC * NRG);
    int ch = rem / NRG, rg = rem - ch * NRG;
    const float2* V = vr + (size_t)cam * N + ch * CHUNK;
    const float4* R = (const float4*)(rec + ((size_t)cam * N + ch * CHUNK) * 16);
    float4* S = (float4*)(cstream + (size_t)gid * CHUNK * 16);
    float cy = (float)(rg * 4) + 1.5f;
    int cnt = 0;
    #pragma unroll
    for (int g = 0; g < CHUNK; g += 64) {
        int n = g + lane;
        bool pass = false;
        if (n < CHUNK) {
            float2 t = V[n];
            pass = fabsf(t.x - cy) <= t.y + 2.01f;   // covers rows rg*4..rg*4+3, alpha<1e-8 outside
        }
        unsigned long long mask = __ballot(pass);
        int pre = __popcll(mask & ((1ull << lane) - 1ull));
        if (pass) {
            int pos = cnt + pre;
            S[pos * 4 + 0] = R[n * 4 + 0];
            S[pos * 4 + 1] = R[n * 4 + 1];
            S[pos * 4 + 2] = R[n * 4 + 2];
            S[pos * 4 + 3] = R[n * 4 + 3];
        }
        cnt += __popcll(mask);
    }
    if (lane == 0) cnts[gid] = cnt;
}

// ---------------------------------------------------------------- chunked alpha compositing
// 1 wave per (cam, chunk, 4-row group); sequential compacted stream, no indirection
__global__ __launch_bounds__(64) void splat_kernel(const float* __restrict__ cstream,
                                                   const int* __restrict__ cnts,
                                                   float* __restrict__ partT,
                                                   unsigned short* __restrict__ partS, int N) {
    __shared__ __align__(16) float4 sRec[CHUNK * 4];   // 6.4 KB
    int rg = blockIdx.x, ch = blockIdx.y, cam = blockIdx.z;
    int lane = threadIdx.x;
    int lid = (cam * NC + ch) * NRG + rg;
    int cnt = cnts[lid];
    const float4* S = (const float4*)(cstream + (size_t)lid * CHUNK * 16);
    for (int t = lane; t < cnt * 4; t += 64) sRec[t] = S[t];
    __syncthreads();
    int r0 = rg * 4;
    float px = (float)lane, py0 = (float)r0;
    float T0 = 1.0f, T1 = 1.0f, T2 = 1.0f, T3 = 1.0f;
    f32x2 accA[17], accB[17];   // rows (r0,r0+1), (r0+2,r0+3)
    #pragma unroll
    for (int c = 0; c < 17; ++c) { accA[c] = (f32x2){0.f, 0.f}; accB[c] = (f32x2){0.f, 0.f}; }
    const float* sRf = (const float*)sRec;
    for (int i = 0; i < cnt; ++i) {
        const float4* rp = sRec + i * 4;
        float4 q0 = rp[0];
        float2 g0 = unpk2h(q0.z);   // hA, hC
        float2 g1 = unpk2h(q0.w);   // nB, op
        float dx = q0.x - px;
        float dy = q0.y - py0;
        float ta = (g0.x * dx) * dx;
        float tb = g1.x * dx;
        float h2 = g0.y + g0.y;
        float p0 = fmaf(dy, fmaf(g0.y, dy, tb), ta);
        float e = fmaf(-h2, dy, g0.y - tb);
        float p1 = p0 + e; e += h2;
        float p2 = p1 + e; e += h2;
        float p3 = p2 + e;
        float a0 = fminf(0.99f, g1.y * __expf(fminf(p0, 0.0f)));
        float a1 = fminf(0.99f, g1.y * __expf(fminf(p1, 0.0f)));
        float a2 = fminf(0.99f, g1.y * __expf(fminf(p2, 0.0f)));
        float a3 = fminf(0.99f, g1.y * __expf(fminf(p3, 0.0f)));
        f32x2 wA = (f32x2){a0 * T0, a1 * T1};
        f32x2 wB = (f32x2){a2 * T2, a3 * T3};
        T0 = fmaf(-T0, a0, T0); T1 = fmaf(-T1, a1, T1);
        T2 = fmaf(-T2, a2, T2); T3 = fmaf(-T3, a3, T3);
        float4 q1 = rp[1], q2 = rp[2];
        float q3x = sRf[i * 16 + 12];
        float2 f01 = unpk2h(q1.x), f23 = unpk2h(q1.y), f45 = unpk2h(q1.z), f67 = unpk2h(q1.w);
        float2 f89 = unpk2h(q2.x), fab = unpk2h(q2.y), fcd = unpk2h(q2.z), fef = unpk2h(q2.w);
        float2 fg_ = unpk2h(q3x);
        accA[0]  += wA * f01.x;  accB[0]  += wB * f01.x;
        accA[1]  += wA * f01.y;  accB[1]  += wB * f01.y;
        accA[2]  += wA * f23.x;  accB[2]  += wB * f23.x;
        accA[3]  += wA * f23.y;  accB[3]  += wB * f23.y;
        accA[4]  += wA * f45.x;  accB[4]  += wB * f45.x;
        accA[5]  += wA * f45.y;  accB[5]  += wB * f45.y;
        accA[6]  += wA * f67.x;  accB[6]  += wB * f67.x;
        accA[7]  += wA * f67.y;  accB[7]  += wB * f67.y;
        accA[8]  += wA * f89.x;  accB[8]  += wB * f89.x;
        accA[9]  += wA * f89.y;  accB[9]  += wB * f89.y;
        accA[10] += wA * fab.x;  accB[10] += wB * fab.x;
        accA[11] += wA * fab.y;  accB[11] += wB * fab.y;
        accA[12] += wA * fcd.x;  accB[12] += wB * fcd.x;
        accA[13] += wA * fcd.y;  accB[13] += wB * fcd.y;
        accA[14] += wA * fef.x;  accB[14] += wB * fef.x;
        accA[15] += wA * fef.y;  accB[15] += wB * fef.y;
        accA[16] += wA * fg_.x;  accB[16] += wB * fg_.x;
    }
    size_t cbase = (size_t)(cam * NC + ch);
    size_t p0i = (size_t)r0 * 64 + lane;
    partT[cbase * P_PIX + p0i]       = T0;
    partT[cbase * P_PIX + p0i + 64]  = T1;
    partT[cbase * P_PIX + p0i + 128] = T2;
    partT[cbase * P_PIX + p0i + 192] = T3;
    _Float16* pS = (_Float16*)partS;
    #pragma unroll
    for (int c = 0; c < 17; ++c) {
        size_t b = (cbase * 17 + c) * P_PIX + p0i;
        pS[b]       = (_Float16)accA[c][0];
        pS[b + 64]  = (_Float16)accA[c][1];
        pS[b + 128] = (_Float16)accB[c][0];
        pS[b + 192] = (_Float16)accB[c][1];
    }
}

// ---------------------------------------------------------------- combine chunks -> fmap (T-prefix in-register)
__global__ __launch_bounds__(256) void combine_kernel(const float* __restrict__ partT,
                                                      const unsigned short* __restrict__ partS,
                                                      float* __restrict__ fmap) {
    int idx = blockIdx.x * 256 + threadIdx.x;
    if (idx >= 2 * 17 * P_PIX) return;
    int p = idx % P_PIX;
    int rem = idx / P_PIX;
    int c = rem % 17;
    int cam = rem / 17;
    const _Float16* pS = (const _Float16*)partS;
    float acc = 0.0f, Tp = 1.0f;
    #pragma unroll 8
    for (int k = 0; k < NC; ++k) {
        size_t cb = (size_t)(cam * NC + k);
        float Tk = partT[cb * P_PIX + p];
        float S = (float)pS[(cb * 17 + c) * P_PIX + p];
        acc = fmaf(Tp, S, acc);
        Tp *= Tk;
    }
    fmap[((size_t)cam * 17 + c) * P_PIX + p] = acc;
}

// ---------------------------------------------------------------- MLP: MFMA all 3 layers
__global__ __launch_bounds__(256, 2) void mlp_kernel(
    const float* __restrict__ embd, const float* __restrict__ sfeat,
    const float* __restrict__ W1, const float* __restrict__ b1,
    const float* __restrict__ g1, const float* __restrict__ be1,
    const float* __restrict__ W2, const float* __restrict__ b2,
    const float* __restrict__ g2, const float* __restrict__ be2,
    const float* __restrict__ W3, const float* __restrict__ b3,
    float* __restrict__ sed, float* __restrict__ ldf) {
    __shared__ __align__(16) unsigned short smem[2 * 64 * MLP_PITCH];
    unsigned short* sX = smem;
    unsigned short* sW = smem + 64 * MLP_PITCH;
    int tid = threadIdx.x, lane = tid & 63, wv = tid >> 6;
    int m = lane & 15, kq = lane >> 4, q4 = kq * 4;
    int tile = blockIdx.x;
    const float* xbase;
    if (tile < 80) {
        int cam = tile / 40; int r = tile - cam * 40;
        int ri = (r * 8) / 5;  // floor(r*64/40)
        xbase = embd + (size_t)cam * 256 * 4096 + ri * 64;
    } else {
        int tt = tile - 80; int cam = tt >> 6;
        xbase = sfeat + (size_t)cam * 256 * 4096 + (tt & 63) * 64;
    }
    const float4* xf4 = (const float4*)xbase;
    for (int idx = tid; idx < 4096; idx += 256) {
        int k = idx >> 4, q = idx & 15;
        float4 xv = xf4[(size_t)k * 1024 + q];
        int r = q * 4;
        sX[(r + 0) * MLP_PITCH + k] = f2bf(xv.x);
        sX[(r + 1) * MLP_PITCH + k] = f2bf(xv.y);
        sX[(r + 2) * MLP_PITCH + k] = f2bf(xv.z);
        sX[(r + 3) * MLP_PITCH + k] = f2bf(xv.w);
    }
    const float4* wf4 = (const float4*)W1;
    for (int idx = tid; idx < 4096; idx += 256) {
        float4 wvv = wf4[idx];
        int n = idx >> 6, kk = (idx & 63) * 4;
        uint2 pk;
        pk.x = (unsigned int)f2bf(wvv.x) | ((unsigned int)f2bf(wvv.y) << 16);
        pk.y = (unsigned int)f2bf(wvv.z) | ((unsigned int)f2bf(wvv.w) << 16);
        *(uint2*)&sW[n * MLP_PITCH + kk] = pk;
    }
    float b1v[4], g1v[4], be1v[4], b2v[4], g2v[4], be2v[4];
    #pragma unroll
    for (int nt = 0; nt < 4; ++nt) {
        int c = nt * 16 + m;
        b1v[nt] = b1[c]; g1v[nt] = g1[c]; be1v[nt] = be1[c];
        b2v[nt] = b2[c]; g2v[nt] = g2[c]; be2v[nt] = be2[c];
    }
    __syncthreads();
    f32x4 acc[4];
    #pragma unroll
    for (int nt = 0; nt < 4; ++nt) acc[nt] = (f32x4){0.f, 0.f, 0.f, 0.f};
    const unsigned short* aptr = sX + (wv * 16 + m) * MLP_PITCH + kq * 8;
    const unsigned short* bptr = sW + m * MLP_PITCH + kq * 8;
    #pragma unroll
    for (int ks = 0; ks < 8; ++ks) {
        short8 af = *(const short8*)(aptr + ks * 32);
        #pragma unroll
        for (int nt = 0; nt < 4; ++nt) {
            short8 bf = *(const short8*)(bptr + nt * 16 * MLP_PITCH + ks * 32);
            acc[nt] = __builtin_amdgcn_mfma_f32_16x16x32_bf16(af, bf, acc[nt], 0, 0, 0);
        }
    }
    __syncthreads();   // done reading sX/sW -> safe to alias
    unsigned short* hbuf  = smem + wv * 16 * 72;
    unsigned short* hbuf2 = smem + (4 + wv) * 16 * 72;
    unsigned short* W2b = sW;
    unsigned short* W3b = sW + 64 * 72;
    for (int i = tid; i < 4096; i += 256)
        W2b[(i >> 6) * 72 + (i & 63)] = f2bf(W2[i]);
    for (int i = tid; i < 2048; i += 256) {
        int n = i >> 6, k = i & 63;
        W3b[n * 72 + k] = (n < 17) ? f2bf(W3[n * 64 + k]) : 0;
    }
    #pragma unroll
    for (int rg = 0; rg < 4; ++rg) {
        float h0 = acc[0][rg] + b1v[0], h1 = acc[1][rg] + b1v[1];
        float h2 = acc[2][rg] + b1v[2], h3 = acc[3][rg] + b1v[3];
        float s = (h0 + h1) + (h2 + h3);
        s += __shfl_xor(s, 1); s += __shfl_xor(s, 2);
        s += __shfl_xor(s, 4); s += __shfl_xor(s, 8);
        float mu = s * (1.0f / 64.0f);
        float d0 = h0 - mu, d1 = h1 - mu, d2 = h2 - mu, d3 = h3 - mu;
        float vs = (d0 * d0 + d1 * d1) + (d2 * d2 + d3 * d3);
        vs += __shfl_xor(vs, 1); vs += __shfl_xor(vs, 2);
        vs += __shfl_xor(vs, 4); vs += __shfl_xor(vs, 8);
        float rstd = 1.0f / sqrtf(vs * (1.0f / 64.0f) + 1e-5f);
        float hn0 = d0 * rstd * g1v[0] + be1v[0]; hn0 = fmaxf(hn0, 0.01f * hn0);
        float hn1 = d1 * rstd * g1v[1] + be1v[1]; hn1 = fmaxf(hn1, 0.01f * hn1);
        float hn2 = d2 * rstd * g1v[2] + be1v[2]; hn2 = fmaxf(hn2, 0.01f * hn2);
        float hn3 = d3 * rstd * g1v[3] + be1v[3]; hn3 = fmaxf(hn3, 0.01f * hn3);
        int rr = (q4 + rg) * 72 + m;
        hbuf[rr] = f2bf(hn0); hbuf[rr + 16] = f2bf(hn1);
        hbuf[rr + 32] = f2bf(hn2); hbuf[rr + 48] = f2bf(hn3);
    }
    __syncthreads();
    f32x4 acc2[4];
    #pragma unroll
    for (int nt = 0; nt < 4; ++nt) acc2[nt] = (f32x4){0.f, 0.f, 0.f, 0.f};
    const unsigned short* a2p = hbuf + m * 72 + kq * 8;
    #pragma unroll
    for (int ks = 0; ks < 2; ++ks) {
        short8 af = *(const short8*)(a2p + ks * 32);
        #pragma unroll
        for (int nt = 0; nt < 4; ++nt) {
            short8 bf = *(const short8*)(W2b + (nt * 16 + m) * 72 + kq * 8 + ks * 32);
            acc2[nt] = __builtin_amdgcn_mfma_f32_16x16x32_bf16(af, bf, acc2[nt], 0, 0, 0);
        }
    }
    #pragma unroll
    for (int rg = 0; rg < 4; ++rg) {
        float h0 = acc2[0][rg] + b2v[0], h1 = acc2[1][rg] + b2v[1];
        float h2 = acc2[2][rg] + b2v[2], h3 = acc2[3][rg] + b2v[3];
        float s = (h0 + h1) + (h2 + h3);
        s += __shfl_xor(s, 1); s += __shfl_xor(s, 2);
        s += __shfl_xor(s, 4); s += __shfl_xor(s, 8);
        float mu = s * (1.0f / 64.0f);
        float d0 = h0 - mu, d1 = h1 - mu, d2 = h2 - mu, d3 = h3 - mu;
        float vs = (d0 * d0 + d1 * d1) + (d2 * d2 + d3 * d3);
        vs += __shfl_xor(vs, 1); vs += __shfl_xor(vs, 2);
        vs += __shfl_xor(vs, 4); vs += __shfl_xor(vs, 8);
        float rstd = 1.0f / sqrtf(vs * (1.0f / 64.0f) + 1e-5f);
        float hn0 = d0 * rstd * g2v[0] + be2v[0]; hn0 = fmaxf(hn0, 0.01f * hn0);
        float hn1 = d1 * rstd * g2v[1] + be2v[1]; hn1 = fmaxf(hn1, 0.01f * hn1);
        float hn2 = d2 * rstd * g2v[2] + be2v[2]; hn2 = fmaxf(hn2, 0.01f * hn2);
        float hn3 = d3 * rstd * g2v[3] + be2v[3]; hn3 = fmaxf(hn3, 0.01f * hn3);
        int rr = (q4 + rg) * 72 + m;
        hbuf2[rr] = f2bf(hn0); hbuf2[rr + 16] = f2bf(hn1);
        hbuf2[rr + 32] = f2bf(hn2); hbuf2[rr + 48] = f2bf(hn3);
    }
    f32x4 acc3[2];
    acc3[0] = (f32x4){0.f, 0.f, 0.f, 0.f};
    acc3[1] = (f32x4){0.f, 0.f, 0.f, 0.f};
    const unsigned short* a3p = hbuf2 + m * 72 + kq * 8;
    #pragma unroll
    for (int ks = 0; ks < 2; ++ks) {
        short8 af = *(const short8*)(a3p + ks * 32);
        #pragma unroll
        for (int nt = 0; nt < 2; ++nt) {
            short8 bf = *(const short8*)(W3b + (nt * 16 + m) * 72 + kq * 8 + ks * 32);
            acc3[nt] = __builtin_amdgcn_mfma_f32_16x16x32_bf16(af, bf, acc3[nt], 0, 0, 0);
        }
    }
    #pragma unroll
    for (int nt = 0; nt < 2; ++nt) {
        int c = nt * 16 + m;
        if (c < 17) {
            float b3v = b3[c];
            #pragma unroll
            for (int rg = 0; rg < 4; ++rg) {
                int row = tile * 64 + wv * 16 + q4 + rg;
                float val = acc3[nt][rg] + b3v;
                if (row < 5120) {
                    int cam = row / 2560; int p = row - cam * 2560;
                    sed[((size_t)cam * 2560 + p) * 17 + c] = val;
                } else {
                    int rr = row - 5120; int cam = rr >> 12; int t = rr & 4095;
                    ldf[((size_t)cam * 17 + c) * 4096 + t] = val;
                }
            }
        }
    }
}

// ---------------------------------------------------------------- mask prototypes
__global__ __launch_bounds__(256) void proto_kernel(const float* __restrict__ masks,
                                                    const float* __restrict__ ldf,
                                                    float* __restrict__ proto) {
    int cam = blockIdx.y, m = blockIdx.x;
    const float* M = masks + ((size_t)cam * 16 + m) * 40000;
    float acc[18];
    #pragma unroll
    for (int j = 0; j < 18; ++j) acc[j] = 0.0f;
    for (int t = threadIdx.x; t < 4096; t += 256) {
        int h = t >> 6, w = t & 63;
        int rh = (h * 25) >> 3, rw = (w * 25) >> 3;
        float lv = M[rh * 200 + rw];
        if (lv != 0.0f) {
            acc[17] += lv;
            const float* L = ldf + (size_t)cam * 17 * 4096 + t;
            #pragma unroll
            for (int c = 0; c < 17; ++c) acc[c] = fmaf(lv, L[(size_t)c * 4096], acc[c]);
        }
    }
    __shared__ float red[4][18];
    int lane = threadIdx.x & 63, wv = threadIdx.x >> 6;
    #pragma unroll
    for (int j = 0; j < 18; ++j) {
        float v = acc[j];
        #pragma unroll
        for (int o = 32; o; o >>= 1) v += __shfl_xor(v, o);
        if (lane == 0) red[wv][j] = v;
    }
    __syncthreads();
    if (threadIdx.x < 17) {
        float sacc = red[0][threadIdx.x] + red[1][threadIdx.x] + red[2][threadIdx.x] + red[3][threadIdx.x];
        float ms = red[0][17] + red[1][17] + red[2][17] + red[3][17];
        proto[((size_t)cam * 16 + m) * 17 + threadIdx.x] = sacc / fmaxf(ms, 1e-6f);
    }
}

__device__ __forceinline__ void block_atomic_add(float v, float* target) {
    #pragma unroll
    for (int o = 32; o; o >>= 1) v += __shfl_xor(v, o);
    __shared__ float sred[4];
    int lane = threadIdx.x & 63, wv = threadIdx.x >> 6;
    if (lane == 0) sred[wv] = v;
    __syncthreads();
    if (threadIdx.x == 0) atomicAdd(target, sred[0] + sred[1] + sred[2] + sred[3]);
}

// ---------------------------------------------------------------- BCE + L1 loss (fused)
__global__ __launch_bounds__(256) void bce_kernel(const float* __restrict__ masks,
                                                  const float* __restrict__ proto,
                                                  const float* __restrict__ fmap,
                                                  const float* __restrict__ sed,
                                                  float* __restrict__ out) {
    int idx = blockIdx.x * 256 + threadIdx.x;
    int p = idx % P_PIX;
    int rem = idx / P_PIX;
    int m = rem & 15, cam = rem >> 4;
    const float* pr = proto + ((size_t)cam * 16 + m) * 17;
    float f[17];
    #pragma unroll
    for (int c = 0; c < 17; ++c) f[c] = fmap[((size_t)cam * 17 + c) * P_PIX + p];
    float sdot = 0;
    #pragma unroll
    for (int c = 0; c < 17; ++c) sdot = fmaf(pr[c], f[c], sdot);
    float prob = 1.0f / (1.0f + __expf(-sdot));
    int px = p & 63, py = p >> 6;
    float src_r = (py + 0.5f) * 5.0f - 0.5f;
    float src_c = (px + 0.5f) * 3.125f - 0.5f;
    int r0 = (int)fminf(fmaxf(floorf(src_r), 0.0f), 199.0f);
    int r1 = min(r0 + 1, 199);
    float wr = fminf(fmaxf(src_r - (float)r0, 0.0f), 1.0f);
    int c0 = (int)fminf(fmaxf(floorf(src_c), 0.0f), 199.0f);
    int c1 = min(c0 + 1, 199);
    float wc = fminf(fmaxf(src_c - (float)c0, 0.0f), 1.0f);
    const float* M = masks + ((size_t)cam * 16 + m) * 40000;
    float v00 = M[r0 * 200 + c0], v01 = M[r0 * 200 + c1];
    float v10 = M[r1 * 200 + c0], v11 = M[r1 * 200 + c1];
    float xr0 = v00 * (1.0f - wr) + v10 * wr;
    float xr1 = v01 * (1.0f - wr) + v11 * wr;
    float frm = xr0 * (1.0f - wc) + xr1 * wc;
    frm = (frm <= 0.5f) ? 0.0f : frm;
    float bce = frm * __logf(prob + 1e-8f) + (1.0f - frm) * __logf(1.0f - prob + 1e-8f);
    float val = bce * (-1.0f / (16.0f * 2560.0f * 2.0f));
    if (m == 0) {   // L1 term, once per (cam, p)
        float ssum = 0.0f;
        const float* sp = sed + ((size_t)cam * P_PIX + p) * 17;
        #pragma unroll
        for (int c = 0; c < 17; ++c) ssum += fabsf(f[c] - sp[c]);
        val += ssum * (1.0f / (43520.0f * 2.0f));
    }
    block_atomic_add(val, out);
}

// ================================================================ launch
extern "C" void kernel_launch(void* const* d_in, const int* in_sizes, int n_in,
                              void* d_out, int out_size, void* d_ws, size_t ws_size,
                              hipStream_t stream) {
    const float* voxel_feats = (const float*)d_in[0];
    const float* opacity     = (const float*)d_in[1];
    const float* sam_embd    = (const float*)d_in[2];
    const float* sam_features= (const float*)d_in[3];
    const float* sam_masks   = (const float*)d_in[4];
    const float* viewmat     = (const float*)d_in[5];
    const float* intrins     = (const float*)d_in[6];
    const float* pc_xyz      = (const float*)d_in[7];
    const float* scales      = (const float*)d_in[8];
    const float* rots        = (const float*)d_in[9];
    const float* W1 = (const float*)d_in[10], *b1 = (const float*)d_in[11];
    const float* g1 = (const float*)d_in[12], *be1 = (const float*)d_in[13];
    const float* W2 = (const float*)d_in[14], *b2 = (const float*)d_in[15];
    const float* g2 = (const float*)d_in[16], *be2 = (const float*)d_in[17];
    const float* W3 = (const float*)d_in[18], *b3 = (const float*)d_in[19];
    float* out = (float*)d_out;
    const int N = in_sizes[7] / 3;  // 12800

    char* w = (char*)d_ws;
    size_t off = 0;
    auto alloc = [&](size_t bytes) -> void* {
        off = (off + 255) & ~(size_t)255;
        void* p = w + off; off += bytes; return p;
    };
    int* rnk  = (int*)alloc((size_t)2 * N * sizeof(int));
    unsigned long long* keys = (unsigned long long*)alloc((size_t)2 * N * 8);
    float* params = (float*)alloc((size_t)7 * 2 * N * 4);
    float* pu  = params,           *pv  = params + 2 * N,  *prad = params + 4 * N;
    float* phA = params + 6 * N,   *phC = params + 8 * N,  *pnB  = params + 10 * N;
    float* pop = params + 12 * N;
    float* rec   = (float*)alloc((size_t)2 * N * 16 * 4);
    float2* vr   = (float2*)alloc((size_t)2 * N * 8);
    float* cstream = (float*)alloc((size_t)2 * NC * NRG * CHUNK * 16 * 4);  // 16.4 MB
    int* cnts = (int*)alloc((size_t)2 * NC * NRG * sizeof(int));
    float* partT = (float*)alloc((size_t)2 * NC * P_PIX * 4);
    unsigned short* partS = (unsigned short*)alloc((size_t)2 * NC * 17 * P_PIX * 2);
    float* fmap  = (float*)alloc((size_t)2 * 17 * P_PIX * 4);
    float* sed   = (float*)alloc((size_t)2 * P_PIX * 17 * 4);
    float* ldf   = (float*)alloc((size_t)2 * 17 * 4096 * 4);
    float* proto = (float*)alloc((size_t)2 * 16 * 17 * 4);

    dim3 gprep((N + 255) / 256, 2);
    prep_kernel<<<gprep, 256, 0, stream>>>(pc_xyz, scales, rots, opacity, viewmat, intrins,
                                           keys, pu, pv, prad, phA, phC, pnB, pop, rnk, out, N);
    dim3 grank((N + 256 * RT - 1) / (256 * RT), (N + RANK_CHUNK - 1) / RANK_CHUNK, 2);
    rank_kernel<<<grank, 256, 0, stream>>>(keys, rnk, N);
    scatter_kernel<<<gprep, 256, 0, stream>>>(rnk, pu, pv, prad, phA, phC, pnB, pop,
                                              voxel_feats, rec, vr, N);
    expand_kernel<<<2 * NC * NRG / 4, 256, 0, stream>>>(vr, rec, cstream, cnts, N);
    dim3 gsplat(NRG, NC, 2);
    splat_kernel<<<gsplat, 64, 0, stream>>>(cstream, cnts, partT, partS, N);
    mlp_kernel<<<208, 256, 0, stream>>>(sam_embd, sam_features, W1, b1, g1, be1,
                                        W2, b2, g2, be2, W3, b3, sed, ldf);
    combine_kernel<<<(2 * 17 * P_PIX + 255) / 256, 256, 0, stream>>>(partT, partS, fmap);
    dim3 gproto(16, 2);
    proto_kernel<<<gproto, 256, 0, stream>>>(sam_masks, ldf, proto);
    bce_kernel<<<(2 * 16 * P_PIX) / 256, 256, 0, stream>>>(sam_masks, proto, fmap, sed, out);
}

// Round 8
// 211.597 us; speedup vs baseline: 1.2583x; 1.1743x over previous
//
#include <hip/hip_runtime.h>
#include <math.h>

#define NPTS   12800
#define P_PIX  2560
#define NC     128         // compositing chunks (NPTS/NC = 100 pts/chunk)
#define CHUNK  100
#define NRG    10          // 4-row groups (40 rows)
#define RANK_CHUNK 400
#define RT     4           // rank keys per thread
#define MLP_PITCH 264      // ushorts per LDS row (256 + 8 pad)

typedef short short8 __attribute__((ext_vector_type(8)));
typedef float f32x4 __attribute__((ext_vector_type(4)));
typedef float f32x2 __attribute__((ext_vector_type(2)));
typedef _Float16 h16x2 __attribute__((ext_vector_type(2)));

union F2H { float f; h16x2 h; unsigned short s[2]; };

__device__ __forceinline__ unsigned short f2bf(float f) {
    unsigned int u = __float_as_uint(f);
    u += 0x7fffu + ((u >> 16) & 1u);   // RNE
    return (unsigned short)(u >> 16);
}

__device__ __forceinline__ float pack2h(float a, float b) {
    union { float f; _Float16 h[2]; } c;
    c.h[0] = (_Float16)a; c.h[1] = (_Float16)b;
    return c.f;
}
__device__ __forceinline__ float2 unpk2h(float w) {
    union { float f; _Float16 h[2]; } c; c.f = w;
    return make_float2((float)c.h[0], (float)c.h[1]);
}

// ---------------------------------------------------------------- per-point projection (+init)
__global__ __launch_bounds__(256) void prep_kernel(
    const float* __restrict__ xyz, const float* __restrict__ scales,
    const float* __restrict__ rots, const float* __restrict__ opacity,
    const float* __restrict__ viewmat, const float* __restrict__ intrins,
    unsigned long long* __restrict__ keys,
    float* __restrict__ pu, float* __restrict__ pv, float* __restrict__ prad,
    float* __restrict__ phA, float* __restrict__ phC, float* __restrict__ pnB,
    float* __restrict__ pop, int* __restrict__ rnk, float* __restrict__ out, int N) {
    int cam = blockIdx.y;
    int i = blockIdx.x * 256 + threadIdx.x;
    if (i >= N) return;
    int idx = cam * N + i;
    rnk[idx] = 0;
    if (idx == 0) out[0] = 0.0f;
    const float* vm = viewmat + cam * 16;
    const float* it = intrins + cam * 4;
    float fx = it[0], fy = it[1], cx = it[2], cy = it[3];
    float R00 = vm[0], R01 = vm[1], R02 = vm[2], t0 = vm[3];
    float R10 = vm[4], R11 = vm[5], R12 = vm[6], t1 = vm[7];
    float R20 = vm[8], R21 = vm[9], R22 = vm[10], t2 = vm[11];
    float X = xyz[i * 3], Y = xyz[i * 3 + 1], Z = xyz[i * 3 + 2];
    float x = R00 * X + R01 * Y + R02 * Z + t0;
    float y = R10 * X + R11 * Y + R12 * Z + t1;
    float z = R20 * X + R21 * Y + R22 * Z + t2;
    float zc = fmaxf(z, 0.001f);
    float iz = 1.0f / zc;
    float u = fx * x * iz + cx;
    float v = fy * y * iz + cy;
    float qw = rots[i * 4], qx = rots[i * 4 + 1], qy = rots[i * 4 + 2], qz = rots[i * 4 + 3];
    float qn = 1.0f / sqrtf(qw * qw + qx * qx + qy * qy + qz * qz);
    qw *= qn; qx *= qn; qy *= qn; qz *= qn;
    float s0 = expf(scales[i * 3]), s1 = expf(scales[i * 3 + 1]), s2 = expf(scales[i * 3 + 2]);
    float Rq[3][3] = {
        {1 - 2 * (qy * qy + qz * qz), 2 * (qx * qy - qw * qz), 2 * (qx * qz + qw * qy)},
        {2 * (qx * qy + qw * qz), 1 - 2 * (qx * qx + qz * qz), 2 * (qy * qz - qw * qx)},
        {2 * (qx * qz - qw * qy), 2 * (qy * qz + qw * qx), 1 - 2 * (qx * qx + qy * qy)}};
    float M[3][3];
    #pragma unroll
    for (int r = 0; r < 3; ++r) { M[r][0] = Rq[r][0] * s0; M[r][1] = Rq[r][1] * s1; M[r][2] = Rq[r][2] * s2; }
    float c3[3][3];
    #pragma unroll
    for (int a = 0; a < 3; ++a)
        #pragma unroll
        for (int b = 0; b < 3; ++b)
            c3[a][b] = M[a][0] * M[b][0] + M[a][1] * M[b][1] + M[a][2] * M[b][2];
    float Rw[3][3] = {{R00, R01, R02}, {R10, R11, R12}, {R20, R21, R22}};
    float Wt[3][3];
    #pragma unroll
    for (int a = 0; a < 3; ++a)
        #pragma unroll
        for (int b = 0; b < 3; ++b)
            Wt[a][b] = Rw[a][0] * c3[0][b] + Rw[a][1] * c3[1][b] + Rw[a][2] * c3[2][b];
    float cw[3][3];
    #pragma unroll
    for (int a = 0; a < 3; ++a)
        #pragma unroll
        for (int b = 0; b < 3; ++b)
            cw[a][b] = Wt[a][0] * Rw[b][0] + Wt[a][1] * Rw[b][1] + Wt[a][2] * Rw[b][2];
    float j00 = fx * iz, j02 = -fx * x * iz * iz;
    float j11 = fy * iz, j12 = -fy * y * iz * iz;
    float c00 = j00 * j00 * cw[0][0] + 2.0f * j00 * j02 * cw[0][2] + j02 * j02 * cw[2][2];
    float c01 = j00 * j11 * cw[0][1] + j00 * j12 * cw[0][2] + j02 * j11 * cw[2][1] + j02 * j12 * cw[2][2];
    float c11 = j11 * j11 * cw[1][1] + 2.0f * j11 * j12 * cw[1][2] + j12 * j12 * cw[2][2];
    float a = c00 + 0.3f, bq = c01, cc = c11 + 0.3f;
    float det = a * cc - bq * bq;
    float A = cc / det, Bc = -bq / det, Cc = a / det;
    float lmin = 0.5f * ((A + Cc) - sqrtf((A - Cc) * (A - Cc) + 4.0f * Bc * Bc));
    lmin = fmaxf(lmin, 1e-20f);
    float opv = (z > 0.2f) ? opacity[i] : 0.0f;
    float rad = -1.0f;
    if (opv > 0.0f) {
        float tcut = logf(opv) + 18.42f;  // ln(op * 1e8)
        if (tcut > 0.0f) rad = sqrtf(2.0f * tcut / lmin);
    }
    pu[idx] = u; pv[idx] = v; prad[idx] = rad;
    phA[idx] = -0.5f * A; phC[idx] = -0.5f * Cc; pnB[idx] = -Bc;
    pop[idx] = opv;
    unsigned int zb = __float_as_uint(z);
    zb = (zb & 0x80000000u) ? ~zb : (zb | 0x80000000u);
    keys[idx] = ((unsigned long long)zb << 32) | (unsigned int)i;
}

// ---------------------------------------------------------------- stable rank, RT keys/thread
__global__ __launch_bounds__(256) void rank_kernel(const unsigned long long* __restrict__ keys,
                                                   int* __restrict__ rnk, int N) {
    __shared__ unsigned long long sk[RANK_CHUNK];
    int cam = blockIdx.z;
    const unsigned long long* K = keys + (size_t)cam * N;
    int jbase = blockIdx.y * RANK_CHUNK;
    int jcnt = min(RANK_CHUNK, N - jbase);
    for (int t = threadIdx.x; t < jcnt; t += 256) sk[t] = K[jbase + t];
    __syncthreads();
    int i0 = blockIdx.x * (256 * RT) + threadIdx.x;
    unsigned long long ki[RT];
    int cnt[RT];
    #pragma unroll
    for (int t = 0; t < RT; ++t) {
        int i = i0 + t * 256;
        ki[t] = (i < N) ? K[i] : 0xFFFFFFFFFFFFFFFFull;
        cnt[t] = 0;
    }
    #pragma unroll 4
    for (int j = 0; j < jcnt; ++j) {
        unsigned long long kj = sk[j];
        #pragma unroll
        for (int t = 0; t < RT; ++t) cnt[t] += (kj < ki[t]) ? 1 : 0;
    }
    #pragma unroll
    for (int t = 0; t < RT; ++t) {
        int i = i0 + t * 256;
        if (i < N && cnt[t]) atomicAdd(rnk + (size_t)cam * N + i, cnt[t]);
    }
}

// ---------------------------------------------------------------- fat kernel: scatter (blocks 0..99) + MLP (blocks 100..307)
// scatter: 16 floats (64 B)/record: [u f32, v f32, (hA,hC) h2, (nB,op) h2, (f0,f1)..(f14,f15) h2 x8, (f16,0) h2, pad]
__global__ __launch_bounds__(256, 2) void scatter_mlp_kernel(
    const int* __restrict__ rnk,
    const float* __restrict__ pu, const float* __restrict__ pv, const float* __restrict__ prad,
    const float* __restrict__ phA, const float* __restrict__ phC, const float* __restrict__ pnB,
    const float* __restrict__ pop, const float* __restrict__ feats,
    float* __restrict__ rec, float2* __restrict__ vr,
    const float* __restrict__ embd, const float* __restrict__ sfeat,
    const float* __restrict__ W1, const float* __restrict__ b1,
    const float* __restrict__ g1, const float* __restrict__ be1,
    const float* __restrict__ W2, const float* __restrict__ b2,
    const float* __restrict__ g2, const float* __restrict__ be2,
    const float* __restrict__ W3, const float* __restrict__ b3,
    float* __restrict__ sed, float* __restrict__ ldf, int N) {
    __shared__ __align__(16) unsigned short smem[2 * 64 * MLP_PITCH];
    int bid = blockIdx.x;
    int tid = threadIdx.x;
    if (bid < 100) {
        // ---------------- scatter ----------------
        int cam = bid / 50;
        int i = (bid % 50) * 256 + tid;
        if (i >= N) return;
        int idx = cam * N + i;
        int r = rnk[idx];
        float* d = rec + ((size_t)cam * N + r) * 16;
        d[0] = pu[idx]; d[1] = pv[idx];
        d[2] = pack2h(phA[idx], phC[idx]);
        d[3] = pack2h(pnB[idx], pop[idx]);
        const float* f = feats + (size_t)i * 17;
        #pragma unroll
        for (int j = 0; j < 8; ++j) d[4 + j] = pack2h(f[2 * j], f[2 * j + 1]);
        d[12] = pack2h(f[16], 0.0f);
        d[13] = 0.0f; d[14] = 0.0f; d[15] = 0.0f;
        vr[(size_t)cam * N + r] = make_float2(pv[idx], prad[idx]);
        return;
    }
    // ---------------- MLP ----------------
    unsigned short* sX = smem;
    unsigned short* sW = smem + 64 * MLP_PITCH;
    int lane = tid & 63, wv = tid >> 6;
    int m = lane & 15, kq = lane >> 4, q4 = kq * 4;
    int tile = bid - 100;
    const float* xbase;
    if (tile < 80) {
        int cam = tile / 40; int r = tile - cam * 40;
        int ri = (r * 8) / 5;  // floor(r*64/40)
        xbase = embd + (size_t)cam * 256 * 4096 + ri * 64;
    } else {
        int tt = tile - 80; int cam = tt >> 6;
        xbase = sfeat + (size_t)cam * 256 * 4096 + (tt & 63) * 64;
    }
    const float4* xf4 = (const float4*)xbase;
    for (int idx = tid; idx < 4096; idx += 256) {
        int k = idx >> 4, q = idx & 15;
        float4 xv = xf4[(size_t)k * 1024 + q];
        int r = q * 4;
        sX[(r + 0) * MLP_PITCH + k] = f2bf(xv.x);
        sX[(r + 1) * MLP_PITCH + k] = f2bf(xv.y);
        sX[(r + 2) * MLP_PITCH + k] = f2bf(xv.z);
        sX[(r + 3) * MLP_PITCH + k] = f2bf(xv.w);
    }
    const float4* wf4 = (const float4*)W1;
    for (int idx = tid; idx < 4096; idx += 256) {
        float4 wvv = wf4[idx];
        int n = idx >> 6, kk = (idx & 63) * 4;
        uint2 pk;
        pk.x = (unsigned int)f2bf(wvv.x) | ((unsigned int)f2bf(wvv.y) << 16);
        pk.y = (unsigned int)f2bf(wvv.z) | ((unsigned int)f2bf(wvv.w) << 16);
        *(uint2*)&sW[n * MLP_PITCH + kk] = pk;
    }
    float b1v[4], g1v[4], be1v[4], b2v[4], g2v[4], be2v[4];
    #pragma unroll
    for (int nt = 0; nt < 4; ++nt) {
        int c = nt * 16 + m;
        b1v[nt] = b1[c]; g1v[nt] = g1[c]; be1v[nt] = be1[c];
        b2v[nt] = b2[c]; g2v[nt] = g2[c]; be2v[nt] = be2[c];
    }
    __syncthreads();
    f32x4 acc[4];
    #pragma unroll
    for (int nt = 0; nt < 4; ++nt) acc[nt] = (f32x4){0.f, 0.f, 0.f, 0.f};
    const unsigned short* aptr = sX + (wv * 16 + m) * MLP_PITCH + kq * 8;
    const unsigned short* bptr = sW + m * MLP_PITCH + kq * 8;
    #pragma unroll
    for (int ks = 0; ks < 8; ++ks) {
        short8 af = *(const short8*)(aptr + ks * 32);
        #pragma unroll
        for (int nt = 0; nt < 4; ++nt) {
            short8 bf = *(const short8*)(bptr + nt * 16 * MLP_PITCH + ks * 32);
            acc[nt] = __builtin_amdgcn_mfma_f32_16x16x32_bf16(af, bf, acc[nt], 0, 0, 0);
        }
    }
    __syncthreads();   // done reading sX/sW -> safe to alias
    unsigned short* hbuf  = smem + wv * 16 * 72;
    unsigned short* hbuf2 = smem + (4 + wv) * 16 * 72;
    unsigned short* W2b = sW;
    unsigned short* W3b = sW + 64 * 72;
    for (int i = tid; i < 4096; i += 256)
        W2b[(i >> 6) * 72 + (i & 63)] = f2bf(W2[i]);
    for (int i = tid; i < 2048; i += 256) {
        int n = i >> 6, k = i & 63;
        W3b[n * 72 + k] = (n < 17) ? f2bf(W3[n * 64 + k]) : 0;
    }
    #pragma unroll
    for (int rg = 0; rg < 4; ++rg) {
        float h0 = acc[0][rg] + b1v[0], h1 = acc[1][rg] + b1v[1];
        float h2 = acc[2][rg] + b1v[2], h3 = acc[3][rg] + b1v[3];
        float s = (h0 + h1) + (h2 + h3);
        s += __shfl_xor(s, 1); s += __shfl_xor(s, 2);
        s += __shfl_xor(s, 4); s += __shfl_xor(s, 8);
        float mu = s * (1.0f / 64.0f);
        float d0 = h0 - mu, d1 = h1 - mu, d2 = h2 - mu, d3 = h3 - mu;
        float vs = (d0 * d0 + d1 * d1) + (d2 * d2 + d3 * d3);
        vs += __shfl_xor(vs, 1); vs += __shfl_xor(vs, 2);
        vs += __shfl_xor(vs, 4); vs += __shfl_xor(vs, 8);
        float rstd = 1.0f / sqrtf(vs * (1.0f / 64.0f) + 1e-5f);
        float hn0 = d0 * rstd * g1v[0] + be1v[0]; hn0 = fmaxf(hn0, 0.01f * hn0);
        float hn1 = d1 * rstd * g1v[1] + be1v[1]; hn1 = fmaxf(hn1, 0.01f * hn1);
        float hn2 = d2 * rstd * g1v[2] + be1v[2]; hn2 = fmaxf(hn2, 0.01f * hn2);
        float hn3 = d3 * rstd * g1v[3] + be1v[3]; hn3 = fmaxf(hn3, 0.01f * hn3);
        int rr = (q4 + rg) * 72 + m;
        hbuf[rr] = f2bf(hn0); hbuf[rr + 16] = f2bf(hn1);
        hbuf[rr + 32] = f2bf(hn2); hbuf[rr + 48] = f2bf(hn3);
    }
    __syncthreads();
    f32x4 acc2[4];
    #pragma unroll
    for (int nt = 0; nt < 4; ++nt) acc2[nt] = (f32x4){0.f, 0.f, 0.f, 0.f};
    const unsigned short* a2p = hbuf + m * 72 + kq * 8;
    #pragma unroll
    for (int ks = 0; ks < 2; ++ks) {
        short8 af = *(const short8*)(a2p + ks * 32);
        #pragma unroll
        for (int nt = 0; nt < 4; ++nt) {
            short8 bf = *(const short8*)(W2b + (nt * 16 + m) * 72 + kq * 8 + ks * 32);
            acc2[nt] = __builtin_amdgcn_mfma_f32_16x16x32_bf16(af, bf, acc2[nt], 0, 0, 0);
        }
    }
    #pragma unroll
    for (int rg = 0; rg < 4; ++rg) {
        float h0 = acc2[0][rg] + b2v[0], h1 = acc2[1][rg] + b2v[1];
        float h2 = acc2[2][rg] + b2v[2], h3 = acc2[3][rg] + b2v[3];
        float s = (h0 + h1) + (h2 + h3);
        s += __shfl_xor(s, 1); s += __shfl_xor(s, 2);
        s += __shfl_xor(s, 4); s += __shfl_xor(s, 8);
        float mu = s * (1.0f / 64.0f);
        float d0 = h0 - mu, d1 = h1 - mu, d2 = h2 - mu, d3 = h3 - mu;
        float vs = (d0 * d0 + d1 * d1) + (d2 * d2 + d3 * d3);
        vs += __shfl_xor(vs, 1); vs += __shfl_xor(vs, 2);
        vs += __shfl_xor(vs, 4); vs += __shfl_xor(vs, 8);
        float rstd = 1.0f / sqrtf(vs * (1.0f / 64.0f) + 1e-5f);
        float hn0 = d0 * rstd * g2v[0] + be2v[0]; hn0 = fmaxf(hn0, 0.01f * hn0);
        float hn1 = d1 * rstd * g2v[1] + be2v[1]; hn1 = fmaxf(hn1, 0.01f * hn1);
        float hn2 = d2 * rstd * g2v[2] + be2v[2]; hn2 = fmaxf(hn2, 0.01f * hn2);
        float hn3 = d3 * rstd * g2v[3] + be2v[3]; hn3 = fmaxf(hn3, 0.01f * hn3);
        int rr = (q4 + rg) * 72 + m;
        hbuf2[rr] = f2bf(hn0); hbuf2[rr + 16] = f2bf(hn1);
        hbuf2[rr + 32] = f2bf(hn2); hbuf2[rr + 48] = f2bf(hn3);
    }
    f32x4 acc3[2];
    acc3[0] = (f32x4){0.f, 0.f, 0.f, 0.f};
    acc3[1] = (f32x4){0.f, 0.f, 0.f, 0.f};
    const unsigned short* a3p = hbuf2 + m * 72 + kq * 8;
    #pragma unroll
    for (int ks = 0; ks < 2; ++ks) {
        short8 af = *(const short8*)(a3p + ks * 32);
        #pragma unroll
        for (int nt = 0; nt < 2; ++nt) {
            short8 bf = *(const short8*)(W3b + (nt * 16 + m) * 72 + kq * 8 + ks * 32);
            acc3[nt] = __builtin_amdgcn_mfma_f32_16x16x32_bf16(af, bf, acc3[nt], 0, 0, 0);
        }
    }
    #pragma unroll
    for (int nt = 0; nt < 2; ++nt) {
        int c = nt * 16 + m;
        if (c < 17) {
            float b3v = b3[c];
            #pragma unroll
            for (int rg = 0; rg < 4; ++rg) {
                int row = tile * 64 + wv * 16 + q4 + rg;
                float val = acc3[nt][rg] + b3v;
                if (row < 5120) {
                    int cam = row / 2560; int p = row - cam * 2560;
                    sed[((size_t)cam * 2560 + p) * 17 + c] = val;
                } else {
                    int rr = row - 5120; int cam = rr >> 12; int t = rr & 4095;
                    ldf[((size_t)cam * 17 + c) * 4096 + t] = val;
                }
            }
        }
    }
}

// ---------------------------------------------------------------- fused splat: LDS compaction + composite
// 1 wave per (cam, chunk, 4-row group); pk_fma_f16 accumulation
__global__ __launch_bounds__(64) void splat_kernel(const float* __restrict__ rec,
                                                   const float2* __restrict__ vr,
                                                   float* __restrict__ partT,
                                                   unsigned short* __restrict__ partS, int N) {
    __shared__ __align__(16) float4 sRaw[CHUNK * 4];   // 6.4 KB
    __shared__ __align__(16) float4 sCmp[CHUNK * 4];   // 6.4 KB
    __shared__ unsigned char sIdx[CHUNK];
    int rg = blockIdx.x, ch = blockIdx.y, cam = blockIdx.z;
    int lane = threadIdx.x;
    const float4* src = (const float4*)(rec + ((size_t)cam * N + ch * CHUNK) * 16);
    for (int t = lane; t < CHUNK * 4; t += 64) sRaw[t] = src[t];
    const float2* V = vr + (size_t)cam * N + ch * CHUNK;
    float cy = (float)(rg * 4) + 1.5f;
    int cnt = 0;
    for (int g = 0; g < CHUNK; g += 64) {
        int n = g + lane;
        bool pass = false;
        if (n < CHUNK) {
            float2 t = V[n];
            pass = fabsf(t.x - cy) <= t.y + 1.51f;
        }
        unsigned long long mask = __ballot(pass);
        int pre = __popcll(mask & ((1ull << lane) - 1ull));
        if (pass) sIdx[cnt + pre] = (unsigned char)n;
        cnt += __popcll(mask);
    }
    __syncthreads();
    for (int l = lane; l < cnt; l += 64) {
        int n = sIdx[l];
        sCmp[l * 4 + 0] = sRaw[n * 4 + 0];
        sCmp[l * 4 + 1] = sRaw[n * 4 + 1];
        sCmp[l * 4 + 2] = sRaw[n * 4 + 2];
        sCmp[l * 4 + 3] = sRaw[n * 4 + 3];
    }
    __syncthreads();
    int r0 = rg * 4;
    float px = (float)lane, py0 = (float)r0;
    float T0 = 1.0f, T1 = 1.0f, T2 = 1.0f, T3 = 1.0f;
    h16x2 acc[4][9];
    #pragma unroll
    for (int r = 0; r < 4; ++r)
        #pragma unroll
        for (int j = 0; j < 9; ++j) acc[r][j] = (h16x2){(_Float16)0.f, (_Float16)0.f};
    const float* sRf = (const float*)sCmp;
    for (int i = 0; i < cnt; ++i) {
        const float4* rp = sCmp + i * 4;
        float4 q0 = rp[0];
        float2 g0 = unpk2h(q0.z);   // hA, hC
        float2 g1 = unpk2h(q0.w);   // nB, op
        float dx = q0.x - px;
        float dy = q0.y - py0;
        float ta = (g0.x * dx) * dx;
        float tb = g1.x * dx;
        float h2 = g0.y + g0.y;
        float p0 = fmaf(dy, fmaf(g0.y, dy, tb), ta);
        float e = fmaf(-h2, dy, g0.y - tb);
        float p1 = p0 + e; e += h2;
        float p2 = p1 + e; e += h2;
        float p3 = p2 + e;
        float a0 = fminf(0.99f, g1.y * __expf(fminf(p0, 0.0f)));
        float a1 = fminf(0.99f, g1.y * __expf(fminf(p1, 0.0f)));
        float a2 = fminf(0.99f, g1.y * __expf(fminf(p2, 0.0f)));
        float a3 = fminf(0.99f, g1.y * __expf(fminf(p3, 0.0f)));
        float w0 = a0 * T0, w1 = a1 * T1, w2 = a2 * T2, w3 = a3 * T3;
        T0 = fmaf(-T0, a0, T0); T1 = fmaf(-T1, a1, T1);
        T2 = fmaf(-T2, a2, T2); T3 = fmaf(-T3, a3, T3);
        h16x2 wh[4];
        wh[0] = (h16x2){(_Float16)w0, (_Float16)w0};
        wh[1] = (h16x2){(_Float16)w1, (_Float16)w1};
        wh[2] = (h16x2){(_Float16)w2, (_Float16)w2};
        wh[3] = (h16x2){(_Float16)w3, (_Float16)w3};
        float4 q1 = rp[1], q2 = rp[2];
        float fg = sRf[i * 16 + 12];
        F2H f[9];
        f[0].f = q1.x; f[1].f = q1.y; f[2].f = q1.z; f[3].f = q1.w;
        f[4].f = q2.x; f[5].f = q2.y; f[6].f = q2.z; f[7].f = q2.w;
        f[8].f = fg;
        #pragma unroll
        for (int r = 0; r < 4; ++r)
            #pragma unroll
            for (int j = 0; j < 9; ++j)
                acc[r][j] += wh[r] * f[j].h;   // v_pk_fma_f16
    }
    size_t cbase = (size_t)(cam * NC + ch);
    size_t p0i = (size_t)r0 * 64 + lane;
    partT[cbase * P_PIX + p0i]       = T0;
    partT[cbase * P_PIX + p0i + 64]  = T1;
    partT[cbase * P_PIX + p0i + 128] = T2;
    partT[cbase * P_PIX + p0i + 192] = T3;
    #pragma unroll
    for (int r = 0; r < 4; ++r) {
        #pragma unroll
        for (int c = 0; c < 17; ++c) {
            F2H v; v.h = acc[r][c >> 1];
            partS[(cbase * 17 + c) * P_PIX + p0i + (size_t)r * 64] = v.s[c & 1];
        }
    }
}

// ---------------------------------------------------------------- fat kernel: combine (blocks 0..339) + proto (blocks 340..371)
__global__ __launch_bounds__(256) void combine_proto_kernel(const float* __restrict__ partT,
                                                            const unsigned short* __restrict__ partS,
                                                            const float* __restrict__ masks,
                                                            const float* __restrict__ ldf,
                                                            float* __restrict__ fmap,
                                                            float* __restrict__ proto) {
    __shared__ float red[4][18];
    int bid = blockIdx.x;
    if (bid < 340) {
        // ---------------- combine ----------------
        int idx = bid * 256 + threadIdx.x;
        int p = idx % P_PIX;
        int rem = idx / P_PIX;
        int c = rem % 17;
        int cam = rem / 17;
        const _Float16* pS = (const _Float16*)partS;
        float acc = 0.0f, Tp = 1.0f;
        #pragma unroll 8
        for (int k = 0; k < NC; ++k) {
            size_t cb = (size_t)(cam * NC + k);
            float Tk = partT[cb * P_PIX + p];
            float S = (float)pS[(cb * 17 + c) * P_PIX + p];
            acc = fmaf(Tp, S, acc);
            Tp *= Tk;
        }
        fmap[((size_t)cam * 17 + c) * P_PIX + p] = acc;
        return;
    }
    // ---------------- proto ----------------
    int t0 = bid - 340;
    int m = t0 & 15, cam = t0 >> 4;
    const float* M = masks + ((size_t)cam * 16 + m) * 40000;
    float acc[18];
    #pragma unroll
    for (int j = 0; j < 18; ++j) acc[j] = 0.0f;
    for (int t = threadIdx.x; t < 4096; t += 256) {
        int h = t >> 6, w = t & 63;
        int rh = (h * 25) >> 3, rw = (w * 25) >> 3;
        float lv = M[rh * 200 + rw];
        if (lv != 0.0f) {
            acc[17] += lv;
            const float* L = ldf + (size_t)cam * 17 * 4096 + t;
            #pragma unroll
            for (int c = 0; c < 17; ++c) acc[c] = fmaf(lv, L[(size_t)c * 4096], acc[c]);
        }
    }
    int lane = threadIdx.x & 63, wv = threadIdx.x >> 6;
    #pragma unroll
    for (int j = 0; j < 18; ++j) {
        float v = acc[j];
        #pragma unroll
        for (int o = 32; o; o >>= 1) v += __shfl_xor(v, o);
        if (lane == 0) red[wv][j] = v;
    }
    __syncthreads();
    if (threadIdx.x < 17) {
        float sacc = red[0][threadIdx.x] + red[1][threadIdx.x] + red[2][threadIdx.x] + red[3][threadIdx.x];
        float ms = red[0][17] + red[1][17] + red[2][17] + red[3][17];
        proto[((size_t)cam * 16 + m) * 17 + threadIdx.x] = sacc / fmaxf(ms, 1e-6f);
    }
}

__device__ __forceinline__ void block_atomic_add(float v, float* target) {
    #pragma unroll
    for (int o = 32; o; o >>= 1) v += __shfl_xor(v, o);
    __shared__ float sred[4];
    int lane = threadIdx.x & 63, wv = threadIdx.x >> 6;
    if (lane == 0) sred[wv] = v;
    __syncthreads();
    if (threadIdx.x == 0) atomicAdd(target, sred[0] + sred[1] + sred[2] + sred[3]);
}

// ---------------------------------------------------------------- BCE + L1 loss (fused)
__global__ __launch_bounds__(256) void bce_kernel(const float* __restrict__ masks,
                                                  const float* __restrict__ proto,
                                                  const float* __restrict__ fmap,
                                                  const float* __restrict__ sed,
                                                  float* __restrict__ out) {
    int idx = blockIdx.x * 256 + threadIdx.x;
    int p = idx % P_PIX;
    int rem = idx / P_PIX;
    int m = rem & 15, cam = rem >> 4;
    const float* pr = proto + ((size_t)cam * 16 + m) * 17;
    float f[17];
    #pragma unroll
    for (int c = 0; c < 17; ++c) f[c] = fmap[((size_t)cam * 17 + c) * P_PIX + p];
    float sdot = 0;
    #pragma unroll
    for (int c = 0; c < 17; ++c) sdot = fmaf(pr[c], f[c], sdot);
    float prob = 1.0f / (1.0f + __expf(-sdot));
    int px = p & 63, py = p >> 6;
    float src_r = (py + 0.5f) * 5.0f - 0.5f;
    float src_c = (px + 0.5f) * 3.125f - 0.5f;
    int r0 = (int)fminf(fmaxf(floorf(src_r), 0.0f), 199.0f);
    int r1 = min(r0 + 1, 199);
    float wr = fminf(fmaxf(src_r - (float)r0, 0.0f), 1.0f);
    int c0 = (int)fminf(fmaxf(floorf(src_c), 0.0f), 199.0f);
    int c1 = min(c0 + 1, 199);
    float wc = fminf(fmaxf(src_c - (float)c0, 0.0f), 1.0f);
    const float* M = masks + ((size_t)cam * 16 + m) * 40000;
    float v00 = M[r0 * 200 + c0], v01 = M[r0 * 200 + c1];
    float v10 = M[r1 * 200 + c0], v11 = M[r1 * 200 + c1];
    float xr0 = v00 * (1.0f - wr) + v10 * wr;
    float xr1 = v01 * (1.0f - wr) + v11 * wr;
    float frm = xr0 * (1.0f - wc) + xr1 * wc;
    frm = (frm <= 0.5f) ? 0.0f : frm;
    float bce = frm * __logf(prob + 1e-8f) + (1.0f - frm) * __logf(1.0f - prob + 1e-8f);
    float val = bce * (-1.0f / (16.0f * 2560.0f * 2.0f));
    if (m == 0) {   // L1 term, once per (cam, p)
        float ssum = 0.0f;
        const float* sp = sed + ((size_t)cam * P_PIX + p) * 17;
        #pragma unroll
        for (int c = 0; c < 17; ++c) ssum += fabsf(f[c] - sp[c]);
        val += ssum * (1.0f / (43520.0f * 2.0f));
    }
    block_atomic_add(val, out);
}

// ================================================================ launch
extern "C" void kernel_launch(void* const* d_in, const int* in_sizes, int n_in,
                              void* d_out, int out_size, void* d_ws, size_t ws_size,
                              hipStream_t stream) {
    const float* voxel_feats = (const float*)d_in[0];
    const float* opacity     = (const float*)d_in[1];
    const float* sam_embd    = (const float*)d_in[2];
    const float* sam_features= (const float*)d_in[3];
    const float* sam_masks   = (const float*)d_in[4];
    const float* viewmat     = (const float*)d_in[5];
    const float* intrins     = (const float*)d_in[6];
    const float* pc_xyz      = (const float*)d_in[7];
    const float* scales      = (const float*)d_in[8];
    const float* rots        = (const float*)d_in[9];
    const float* W1 = (const float*)d_in[10], *b1 = (const float*)d_in[11];
    const float* g1 = (const float*)d_in[12], *be1 = (const float*)d_in[13];
    const float* W2 = (const float*)d_in[14], *b2 = (const float*)d_in[15];
    const float* g2 = (const float*)d_in[16], *be2 = (const float*)d_in[17];
    const float* W3 = (const float*)d_in[18], *b3 = (const float*)d_in[19];
    float* out = (float*)d_out;
    const int N = in_sizes[7] / 3;  // 12800

    char* w = (char*)d_ws;
    size_t off = 0;
    auto alloc = [&](size_t bytes) -> void* {
        off = (off + 255) & ~(size_t)255;
        void* p = w + off; off += bytes; return p;
    };
    int* rnk  = (int*)alloc((size_t)2 * N * sizeof(int));
    unsigned long long* keys = (unsigned long long*)alloc((size_t)2 * N * 8);
    float* params = (float*)alloc((size_t)7 * 2 * N * 4);
    float* pu  = params,           *pv  = params + 2 * N,  *prad = params + 4 * N;
    float* phA = params + 6 * N,   *phC = params + 8 * N,  *pnB  = params + 10 * N;
    float* pop = params + 12 * N;
    float* rec   = (float*)alloc((size_t)2 * N * 16 * 4);
    float2* vr   = (float2*)alloc((size_t)2 * N * 8);
    float* partT = (float*)alloc((size_t)2 * NC * P_PIX * 4);
    unsigned short* partS = (unsigned short*)alloc((size_t)2 * NC * 17 * P_PIX * 2);
    float* fmap  = (float*)alloc((size_t)2 * 17 * P_PIX * 4);
    float* sed   = (float*)alloc((size_t)2 * P_PIX * 17 * 4);
    float* ldf   = (float*)alloc((size_t)2 * 17 * 4096 * 4);
    float* proto = (float*)alloc((size_t)2 * 16 * 17 * 4);

    dim3 gprep((N + 255) / 256, 2);
    prep_kernel<<<gprep, 256, 0, stream>>>(pc_xyz, scales, rots, opacity, viewmat, intrins,
                                           keys, pu, pv, prad, phA, phC, pnB, pop, rnk, out, N);
    dim3 grank((N + 256 * RT - 1) / (256 * RT), (N + RANK_CHUNK - 1) / RANK_CHUNK, 2);
    rank_kernel<<<grank, 256, 0, stream>>>(keys, rnk, N);
    scatter_mlp_kernel<<<308, 256, 0, stream>>>(rnk, pu, pv, prad, phA, phC, pnB, pop,
                                                voxel_feats, rec, vr,
                                                sam_embd, sam_features, W1, b1, g1, be1,
                                                W2, b2, g2, be2, W3, b3, sed, ldf, N);
    dim3 gsplat(NRG, NC, 2);
    splat_kernel<<<gsplat, 64, 0, stream>>>(rec, vr, partT, partS, N);
    combine_proto_kernel<<<372, 256, 0, stream>>>(partT, partS, sam_masks, ldf, fmap, proto);
    bce_kernel<<<(2 * 16 * P_PIX) / 256, 256, 0, stream>>>(sam_masks, proto, fmap, sed, out);
}